// Round 2
// baseline (1114.557 us; speedup 1.0000x reference)
//
#include <hip/hip_runtime.h>

// SparseLinear: out[b, j] = sum_{e: dst[e]==j} values[e] * x[b, src[e]] + bias[j]
// Inputs: x f32 (B,N_IN,1) | values f32 (NNZ,) | bias f32 (N_OUT,1)
//         indices i32 (2,NNZ) row0=src row1=dst | n_out scalar
// Output: f32 (B, N_OUT, 1)
//
// Strategy: counting-sort edges into dst-chunks of CH outputs, then per-chunk
// LDS accumulation (no global atomics).

#define CH_LOG 6
#define CH 64          // dst nodes per chunk
#define PACK_SHIFT 20  // src in bits [0,20), dst-local in bits [20,26)

// ---------- transpose x (B=32, N) -> xT (N, 32) ----------
__global__ void xpose_in_kernel(const float* __restrict__ x, float* __restrict__ xT, int N) {
    __shared__ float tile[32][33];
    int n0 = blockIdx.x * 32;
    int tx = threadIdx.x;
    int ty = threadIdx.y;
    if (n0 + tx < N) tile[ty][tx] = x[ty * (long)N + n0 + tx];
    __syncthreads();
    if (n0 + ty < N) xT[(long)(n0 + ty) * 32 + tx] = tile[tx][ty];
}

// ---------- pass 1: per-chunk edge counts (LDS histogram per block) ----------
__global__ void count_kernel(const int* __restrict__ dst, int* __restrict__ counts,
                             int nnz, int nchunk) {
    extern __shared__ int hist[];
    for (int i = threadIdx.x; i < nchunk; i += blockDim.x) hist[i] = 0;
    __syncthreads();
    int tid = blockIdx.x * blockDim.x + threadIdx.x;
    int nthreads = gridDim.x * blockDim.x;
    int nvec = nnz >> 2;
    const int4* dst4 = (const int4*)dst;
    for (int i = tid; i < nvec; i += nthreads) {
        int4 d = dst4[i];
        atomicAdd(&hist[d.x >> CH_LOG], 1);
        atomicAdd(&hist[d.y >> CH_LOG], 1);
        atomicAdd(&hist[d.z >> CH_LOG], 1);
        atomicAdd(&hist[d.w >> CH_LOG], 1);
    }
    for (int e = (nvec << 2) + tid; e < nnz; e += nthreads)
        atomicAdd(&hist[dst[e] >> CH_LOG], 1);
    __syncthreads();
    for (int i = threadIdx.x; i < nchunk; i += blockDim.x) {
        int h = hist[i];
        if (h) atomicAdd(&counts[i], h);
    }
}

// ---------- pass 1b: exclusive scan of counts -> offsets; counts becomes cursors ----------
// single block, 256 threads, nchunk <= 4096
__global__ void scan_kernel(int* __restrict__ counts, int* __restrict__ offsets, int nchunk) {
    __shared__ int wave_sums[4];
    int tid = threadIdx.x;
    int items = (nchunk + 255) >> 8;   // <= 16
    int base = tid * items;
    int local[16];
    int sum = 0;
    for (int k = 0; k < items; ++k) {
        int idx = base + k;
        int c = (idx < nchunk) ? counts[idx] : 0;
        local[k] = sum;       // thread-local exclusive prefix
        sum += c;
    }
    int lane = tid & 63, wid = tid >> 6;
    int inc = sum;
    for (int d = 1; d < 64; d <<= 1) {
        int n = __shfl_up(inc, d, 64);
        if (lane >= d) inc += n;
    }
    if (lane == 63) wave_sums[wid] = inc;
    __syncthreads();
    if (tid == 0) {
        int s = 0;
        for (int w = 0; w < 4; ++w) { int t = wave_sums[w]; wave_sums[w] = s; s += t; }
    }
    __syncthreads();
    int excl = inc - sum + wave_sums[wid];  // exclusive prefix for this thread
    for (int k = 0; k < items; ++k) {
        int idx = base + k;
        if (idx < nchunk) {
            int off = excl + local[k];
            offsets[idx] = off;
            counts[idx] = off;   // reuse as running cursor for scatter pass
        }
    }
    if (tid == 255) offsets[nchunk] = excl + sum;
}

// ---------- pass 2: scatter edges into chunk-binned (packed, value) records ----------
template <bool FULL>
__global__ void scatter_kernel(const int* __restrict__ src, const int* __restrict__ dst,
                               const float* __restrict__ val, int* __restrict__ cursors,
                               uint2* __restrict__ binned, unsigned* __restrict__ binned_eid,
                               int nnz) {
    int tid = blockIdx.x * blockDim.x + threadIdx.x;
    int nthreads = gridDim.x * blockDim.x;
    int nvec = nnz >> 2;
    const int4* src4 = (const int4*)src;
    const int4* dst4 = (const int4*)dst;
    const float4* val4 = (const float4*)val;
    for (int i = tid; i < nvec; i += nthreads) {
        int4 d = dst4[i];
        if (FULL) {
            int4 s = src4[i];
            float4 v = val4[i];
            int p;
            p = atomicAdd(&cursors[d.x >> CH_LOG], 1);
            binned[p] = make_uint2((unsigned)s.x | ((unsigned)(d.x & (CH - 1)) << PACK_SHIFT), __float_as_uint(v.x));
            p = atomicAdd(&cursors[d.y >> CH_LOG], 1);
            binned[p] = make_uint2((unsigned)s.y | ((unsigned)(d.y & (CH - 1)) << PACK_SHIFT), __float_as_uint(v.y));
            p = atomicAdd(&cursors[d.z >> CH_LOG], 1);
            binned[p] = make_uint2((unsigned)s.z | ((unsigned)(d.z & (CH - 1)) << PACK_SHIFT), __float_as_uint(v.z));
            p = atomicAdd(&cursors[d.w >> CH_LOG], 1);
            binned[p] = make_uint2((unsigned)s.w | ((unsigned)(d.w & (CH - 1)) << PACK_SHIFT), __float_as_uint(v.w));
        } else {
            int e = i << 2;
            int p;
            p = atomicAdd(&cursors[d.x >> CH_LOG], 1); binned_eid[p] = (unsigned)(e + 0);
            p = atomicAdd(&cursors[d.y >> CH_LOG], 1); binned_eid[p] = (unsigned)(e + 1);
            p = atomicAdd(&cursors[d.z >> CH_LOG], 1); binned_eid[p] = (unsigned)(e + 2);
            p = atomicAdd(&cursors[d.w >> CH_LOG], 1); binned_eid[p] = (unsigned)(e + 3);
        }
    }
    for (int e = (nvec << 2) + tid; e < nnz; e += nthreads) {
        int d = dst[e];
        int p = atomicAdd(&cursors[d >> CH_LOG], 1);
        if (FULL) {
            binned[p] = make_uint2((unsigned)src[e] | ((unsigned)(d & (CH - 1)) << PACK_SHIFT),
                                   __float_as_uint(val[e]));
        } else {
            binned_eid[p] = (unsigned)e;
        }
    }
}

// ---------- pass 3: per-chunk gather + LDS accumulate + coalesced store ----------
template <bool FULL>
__global__ void gather_chunk_kernel(const uint2* __restrict__ binned,
                                    const unsigned* __restrict__ binned_eid,
                                    const int* __restrict__ offsets,
                                    const int* __restrict__ src, const int* __restrict__ dst,
                                    const float* __restrict__ val,
                                    const float* __restrict__ xT, const float* __restrict__ bias,
                                    float* __restrict__ out, int n_out) {
    __shared__ float acc[CH * 33];   // padded: addr = jl*33 + b -> bank (jl+b)%32, conflict-free
    int c = blockIdx.x;
    int j0 = c << CH_LOG;
    for (int i = threadIdx.x; i < CH * 33; i += blockDim.x) acc[i] = 0.0f;
    __syncthreads();

    int beg = offsets[c], end = offsets[c + 1];
    int cnt = end - beg;
    int g = threadIdx.x >> 5;   // 8 groups of 32 lanes
    int b = threadIdx.x & 31;   // batch lane
    int per = (cnt + 7) >> 3;
    int gbeg = beg + g * per;
    int gend = min(gbeg + per, end);
#pragma unroll 4
    for (int e = gbeg; e < gend; ++e) {
        int s, jl;
        float v;
        if (FULL) {
            uint2 ed = binned[e];
            s = (int)(ed.x & ((1u << PACK_SHIFT) - 1));
            jl = (int)(ed.x >> PACK_SHIFT);
            v = __uint_as_float(ed.y);
        } else {
            int eid = (int)binned_eid[e];
            s = src[eid];
            jl = dst[eid] & (CH - 1);
            v = val[eid];
        }
        float xv = xT[s * 32 + b];
        atomicAdd(&acc[jl * 33 + b], v * xv);
    }
    __syncthreads();

    for (int i = threadIdx.x; i < CH * 32; i += blockDim.x) {
        int bb = i >> CH_LOG;        // batch index
        int jl = i & (CH - 1);
        int j = j0 + jl;
        if (j < n_out) out[bb * n_out + j] = acc[jl * 33 + bb] + bias[j];
    }
}

// ================= fallback kernels (round-1 atomic path) =================
__global__ void edge_kernel(const float* __restrict__ xT, const float* __restrict__ values,
                            const int* __restrict__ src, const int* __restrict__ dst,
                            float* __restrict__ accT, int nnz) {
    int tid = blockIdx.x * blockDim.x + threadIdx.x;
    int lane_b = tid & 31;
    int e0 = tid >> 5;
    int estride = (gridDim.x * blockDim.x) >> 5;
    for (int e = e0; e < nnz; e += estride) {
        int s = src[e];
        int d = dst[e];
        float v = values[e];
        atomicAdd(&accT[(long)d * 32 + lane_b], v * xT[(long)s * 32 + lane_b]);
    }
}

__global__ void xpose_out_kernel(const float* __restrict__ accT, const float* __restrict__ bias,
                                 float* __restrict__ out, int N) {
    __shared__ float tile[32][33];
    int j0 = blockIdx.x * 32;
    int tx = threadIdx.x;
    int ty = threadIdx.y;
    if (j0 + ty < N) tile[ty][tx] = accT[(long)(j0 + ty) * 32 + tx];
    __syncthreads();
    if (j0 + tx < N) out[ty * (long)N + j0 + tx] = tile[tx][ty] + bias[j0 + tx];
}

__global__ void edge_direct_kernel(const float* __restrict__ x, const float* __restrict__ values,
                                   const int* __restrict__ src, const int* __restrict__ dst,
                                   float* __restrict__ out, int nnz, int N_IN, int N_OUT) {
    int tid = blockIdx.x * blockDim.x + threadIdx.x;
    int lane_b = tid & 31;
    int e0 = tid >> 5;
    int estride = (gridDim.x * blockDim.x) >> 5;
    for (int e = e0; e < nnz; e += estride) {
        atomicAdd(&out[(long)lane_b * N_OUT + dst[e]],
                  values[e] * x[(long)lane_b * N_IN + src[e]]);
    }
}

__global__ void init_out_bias_kernel(float* __restrict__ out, const float* __restrict__ bias,
                                     int N_OUT, int B) {
    long i = (long)blockIdx.x * blockDim.x + threadIdx.x;
    if (i < (long)N_OUT * B) out[i] = bias[i % N_OUT];
}

extern "C" void kernel_launch(void* const* d_in, const int* in_sizes, int n_in,
                              void* d_out, int out_size, void* d_ws, size_t ws_size,
                              hipStream_t stream) {
    const float* x      = (const float*)d_in[0];
    const float* values = (const float*)d_in[1];
    const float* bias   = (const float*)d_in[2];
    const int*   idx    = (const int*)d_in[3];

    const int NNZ   = in_sizes[1];
    const int N_OUT = in_sizes[2];
    const int B     = out_size / N_OUT;
    const int N_IN  = in_sizes[0] / B;

    const int* src = idx;
    const int* dst = idx + NNZ;
    float* out = (float*)d_out;

    const int nchunk = (N_OUT + CH - 1) >> CH_LOG;

    const size_t xT_b     = (size_t)N_IN * 32 * sizeof(float);
    const size_t full_b   = (size_t)NNZ * sizeof(uint2);
    const size_t eid_b    = (size_t)NNZ * sizeof(unsigned);
    const size_t counts_b = (size_t)nchunk * sizeof(int);
    const size_t offs_b   = (size_t)(nchunk + 1) * sizeof(int);

    const size_t need_full = xT_b + full_b + counts_b + offs_b;
    const size_t need_eid  = xT_b + eid_b + counts_b + offs_b;

    const bool shape_ok = (B == 32) && (N_IN < (1 << PACK_SHIFT)) && (nchunk <= 4096) && (NNZ > 0);

    if (shape_ok && ws_size >= need_eid) {
        const bool full = (ws_size >= need_full);
        char* p = (char*)d_ws;
        float* xT = (float*)p;                 p += xT_b;
        uint2* binned = (uint2*)p;
        unsigned* binned_eid = (unsigned*)p;   p += (full ? full_b : eid_b);
        int* counts = (int*)p;                 p += counts_b;
        int* offsets = (int*)p;

        {   // transpose x -> xT
            dim3 blk(32, 32);
            xpose_in_kernel<<<(N_IN + 31) / 32, blk, 0, stream>>>(x, xT, N_IN);
        }
        hipMemsetAsync(counts, 0, counts_b, stream);
        count_kernel<<<1024, 256, nchunk * sizeof(int), stream>>>(dst, counts, NNZ, nchunk);
        scan_kernel<<<1, 256, 0, stream>>>(counts, offsets, nchunk);
        if (full) {
            scatter_kernel<true><<<2048, 256, 0, stream>>>(src, dst, values, counts, binned, binned_eid, NNZ);
            gather_chunk_kernel<true><<<nchunk, 256, 0, stream>>>(binned, binned_eid, offsets,
                                                                  src, dst, values, xT, bias, out, N_OUT);
        } else {
            scatter_kernel<false><<<2048, 256, 0, stream>>>(src, dst, values, counts, binned, binned_eid, NNZ);
            gather_chunk_kernel<false><<<nchunk, 256, 0, stream>>>(binned, binned_eid, offsets,
                                                                   src, dst, values, xT, bias, out, N_OUT);
        }
    } else if (B == 32 && ws_size >= xT_b + (size_t)N_OUT * 32 * sizeof(float)) {
        // round-1 fallback: global atomics into accT
        float* xT = (float*)d_ws;
        float* accT = (float*)((char*)d_ws + xT_b);
        dim3 blk(32, 32);
        xpose_in_kernel<<<(N_IN + 31) / 32, blk, 0, stream>>>(x, xT, N_IN);
        hipMemsetAsync(accT, 0, (size_t)N_OUT * 32 * sizeof(float), stream);
        edge_kernel<<<4096, 256, 0, stream>>>(xT, values, src, dst, accT, NNZ);
        xpose_out_kernel<<<(N_OUT + 31) / 32, blk, 0, stream>>>(accT, bias, out, N_OUT);
    } else {
        long total = (long)N_OUT * B;
        init_out_bias_kernel<<<(int)((total + 255) / 256), 256, 0, stream>>>(out, bias, N_OUT, B);
        edge_direct_kernel<<<4096, 256, 0, stream>>>(x, values, src, dst, out, NNZ, N_IN, N_OUT);
    }
}

// Round 3
// 1105.466 us; speedup vs baseline: 1.0082x; 1.0082x over previous
//
#include <hip/hip_runtime.h>

// SparseLinear: out[b, j] = sum_{e: dst[e]==j} values[e] * x[b, src[e]] + bias[j]
// Inputs: x f32 (B,N_IN,1) | values f32 (NNZ,) | bias f32 (N_OUT,1)
//         indices i32 (2,NNZ) row0=src row1=dst | n_out scalar
// Output: f32 (B, N_OUT, 1)
//
// Pipeline: transpose x -> count edges per dst-chunk -> scan -> scatter edges
// into chunk bins -> per-chunk LDS accumulate (no global atomics).
// Round-3 change: manual 8-wide ILP in scatter + gather (round-2 was
// latency-bound at ILP=1: 12 VGPRs, VALUBusy 3%).

#define CH_LOG 6
#define CH 64           // dst nodes per chunk
#define PACK_SHIFT 20   // src in bits [0,20), dst-local in [20,26)
#define SRC_MASK ((1u << PACK_SHIFT) - 1u)

// ---------- transpose x (B=32, N) -> xT (N, 32) ----------
__global__ void xpose_in_kernel(const float* __restrict__ x, float* __restrict__ xT, int N) {
    __shared__ float tile[32][33];
    int n0 = blockIdx.x * 32;
    int tx = threadIdx.x;
    int ty = threadIdx.y;
    if (n0 + tx < N) tile[ty][tx] = x[ty * (long)N + n0 + tx];
    __syncthreads();
    if (n0 + ty < N) xT[(long)(n0 + ty) * 32 + tx] = tile[tx][ty];
}

// ---------- pass 1: per-chunk edge counts ----------
__global__ void count_kernel(const int* __restrict__ dst, int* __restrict__ counts,
                             int nnz, int nchunk) {
    extern __shared__ int hist[];
    for (int i = threadIdx.x; i < nchunk; i += blockDim.x) hist[i] = 0;
    __syncthreads();
    int tid = blockIdx.x * blockDim.x + threadIdx.x;
    int nthreads = gridDim.x * blockDim.x;
    int nvec = nnz >> 2;
    const int4* dst4 = (const int4*)dst;
    for (int i = tid; i < nvec; i += nthreads) {
        int4 d = dst4[i];
        atomicAdd(&hist[d.x >> CH_LOG], 1);
        atomicAdd(&hist[d.y >> CH_LOG], 1);
        atomicAdd(&hist[d.z >> CH_LOG], 1);
        atomicAdd(&hist[d.w >> CH_LOG], 1);
    }
    for (int e = (nvec << 2) + tid; e < nnz; e += nthreads)
        atomicAdd(&hist[dst[e] >> CH_LOG], 1);
    __syncthreads();
    for (int i = threadIdx.x; i < nchunk; i += blockDim.x) {
        int h = hist[i];
        if (h) atomicAdd(&counts[i], h);
    }
}

// ---------- pass 1b: exclusive scan; counts becomes running cursors ----------
// single block, 256 threads, nchunk <= 4096
__global__ void scan_kernel(int* __restrict__ counts, int* __restrict__ offsets, int nchunk) {
    __shared__ int wave_sums[4];
    int tid = threadIdx.x;
    int items = (nchunk + 255) >> 8;   // <= 16
    int base = tid * items;
    int local[16];
    int sum = 0;
    for (int k = 0; k < items; ++k) {
        int idx = base + k;
        int c = (idx < nchunk) ? counts[idx] : 0;
        local[k] = sum;
        sum += c;
    }
    int lane = tid & 63, wid = tid >> 6;
    int inc = sum;
    for (int d = 1; d < 64; d <<= 1) {
        int n = __shfl_up(inc, d, 64);
        if (lane >= d) inc += n;
    }
    if (lane == 63) wave_sums[wid] = inc;
    __syncthreads();
    if (tid == 0) {
        int s = 0;
        for (int w = 0; w < 4; ++w) { int t = wave_sums[w]; wave_sums[w] = s; s += t; }
    }
    __syncthreads();
    int excl = inc - sum + wave_sums[wid];
    for (int k = 0; k < items; ++k) {
        int idx = base + k;
        if (idx < nchunk) {
            int off = excl + local[k];
            offsets[idx] = off;
            counts[idx] = off;
        }
    }
    if (tid == 255) offsets[nchunk] = excl + sum;
}

// ---------- pass 2: scatter edges into chunk bins, 8-wide ILP ----------
__device__ __forceinline__ void scat1(int s, int d, float v, int* cursors, uint2* binned,
                                      int& p, uint2& rec) {
    p = atomicAdd(&cursors[d >> CH_LOG], 1);
    rec = make_uint2((unsigned)s | ((unsigned)(d & (CH - 1)) << PACK_SHIFT), __float_as_uint(v));
}

__global__ void scatter_full_kernel(const int* __restrict__ src, const int* __restrict__ dst,
                                    const float* __restrict__ val, int* __restrict__ cursors,
                                    uint2* __restrict__ binned, int nnz) {
    int tid = blockIdx.x * blockDim.x + threadIdx.x;
    int nthreads = gridDim.x * blockDim.x;
    int nvec = nnz >> 2;
    const int4* src4 = (const int4*)src;
    const int4* dst4 = (const int4*)dst;
    const float4* val4 = (const float4*)val;
    // two int4 lanes per iteration -> 8 independent atomic chains
    for (int i = tid; i < nvec; i += 2 * nthreads) {
        int j = i + nthreads;
        bool hasj = (j < nvec);
        int4 dA = dst4[i];
        int4 sA = src4[i];
        float4 vA = val4[i];
        int4 dB, sB; float4 vB;
        if (hasj) { dB = dst4[j]; sB = src4[j]; vB = val4[j]; }
        int p0, p1, p2, p3, p4 = 0, p5 = 0, p6 = 0, p7 = 0;
        uint2 r0, r1, r2, r3, r4, r5, r6, r7;
        scat1(sA.x, dA.x, vA.x, cursors, binned, p0, r0);
        scat1(sA.y, dA.y, vA.y, cursors, binned, p1, r1);
        scat1(sA.z, dA.z, vA.z, cursors, binned, p2, r2);
        scat1(sA.w, dA.w, vA.w, cursors, binned, p3, r3);
        if (hasj) {
            scat1(sB.x, dB.x, vB.x, cursors, binned, p4, r4);
            scat1(sB.y, dB.y, vB.y, cursors, binned, p5, r5);
            scat1(sB.z, dB.z, vB.z, cursors, binned, p6, r6);
            scat1(sB.w, dB.w, vB.w, cursors, binned, p7, r7);
        }
        binned[p0] = r0; binned[p1] = r1; binned[p2] = r2; binned[p3] = r3;
        if (hasj) { binned[p4] = r4; binned[p5] = r5; binned[p6] = r6; binned[p7] = r7; }
    }
    for (int e = (nvec << 2) + tid; e < nnz; e += nthreads) {
        int d = dst[e];
        int p = atomicAdd(&cursors[d >> CH_LOG], 1);
        binned[p] = make_uint2((unsigned)src[e] | ((unsigned)(d & (CH - 1)) << PACK_SHIFT),
                               __float_as_uint(val[e]));
    }
}

// ---------- pass 3: per-chunk gather + LDS accumulate, 8-wide ILP ----------
__global__ __launch_bounds__(256) void gather_chunk_kernel(
        const uint2* __restrict__ binned, const int* __restrict__ offsets,
        const float* __restrict__ xT, const float* __restrict__ bias,
        float* __restrict__ out, int n_out) {
    __shared__ float acc[CH * 33];   // bank (jl+b)%32 -> conflict-free
    int c = blockIdx.x;
    int j0 = c << CH_LOG;
    for (int i = threadIdx.x; i < CH * 33; i += blockDim.x) acc[i] = 0.0f;
    __syncthreads();

    int beg = offsets[c], end = offsets[c + 1];
    int cnt = end - beg;
    int g = threadIdx.x >> 5;     // 8 groups of 32 lanes
    int b = threadIdx.x & 31;     // batch lane
    int per = (cnt + 7) >> 3;
    int gbeg = beg + g * per;
    int gend = min(gbeg + per, end);

    int e = gbeg;
    for (; e + 8 <= gend; e += 8) {
        uint2 r0 = binned[e + 0], r1 = binned[e + 1], r2 = binned[e + 2], r3 = binned[e + 3];
        uint2 r4 = binned[e + 4], r5 = binned[e + 5], r6 = binned[e + 6], r7 = binned[e + 7];
        float x0 = xT[(r0.x & SRC_MASK) * 32 + b];
        float x1 = xT[(r1.x & SRC_MASK) * 32 + b];
        float x2 = xT[(r2.x & SRC_MASK) * 32 + b];
        float x3 = xT[(r3.x & SRC_MASK) * 32 + b];
        float x4 = xT[(r4.x & SRC_MASK) * 32 + b];
        float x5 = xT[(r5.x & SRC_MASK) * 32 + b];
        float x6 = xT[(r6.x & SRC_MASK) * 32 + b];
        float x7 = xT[(r7.x & SRC_MASK) * 32 + b];
        atomicAdd(&acc[(r0.x >> PACK_SHIFT) * 33 + b], __uint_as_float(r0.y) * x0);
        atomicAdd(&acc[(r1.x >> PACK_SHIFT) * 33 + b], __uint_as_float(r1.y) * x1);
        atomicAdd(&acc[(r2.x >> PACK_SHIFT) * 33 + b], __uint_as_float(r2.y) * x2);
        atomicAdd(&acc[(r3.x >> PACK_SHIFT) * 33 + b], __uint_as_float(r3.y) * x3);
        atomicAdd(&acc[(r4.x >> PACK_SHIFT) * 33 + b], __uint_as_float(r4.y) * x4);
        atomicAdd(&acc[(r5.x >> PACK_SHIFT) * 33 + b], __uint_as_float(r5.y) * x5);
        atomicAdd(&acc[(r6.x >> PACK_SHIFT) * 33 + b], __uint_as_float(r6.y) * x6);
        atomicAdd(&acc[(r7.x >> PACK_SHIFT) * 33 + b], __uint_as_float(r7.y) * x7);
    }
    for (; e < gend; ++e) {
        uint2 r = binned[e];
        float xv = xT[(r.x & SRC_MASK) * 32 + b];
        atomicAdd(&acc[(r.x >> PACK_SHIFT) * 33 + b], __uint_as_float(r.y) * xv);
    }
    __syncthreads();

    for (int i = threadIdx.x; i < CH * 32; i += blockDim.x) {
        int bb = i >> CH_LOG;
        int jl = i & (CH - 1);
        int j = j0 + jl;
        if (j < n_out) out[bb * n_out + j] = acc[jl * 33 + bb] + bias[j];
    }
}

// ================= fallback kernels =================
__global__ void edge_kernel(const float* __restrict__ xT, const float* __restrict__ values,
                            const int* __restrict__ src, const int* __restrict__ dst,
                            float* __restrict__ accT, int nnz) {
    int tid = blockIdx.x * blockDim.x + threadIdx.x;
    int lane_b = tid & 31;
    int e0 = tid >> 5;
    int estride = (gridDim.x * blockDim.x) >> 5;
    for (int e = e0; e < nnz; e += estride) {
        atomicAdd(&accT[(long)dst[e] * 32 + lane_b], values[e] * xT[(long)src[e] * 32 + lane_b]);
    }
}

__global__ void xpose_out_kernel(const float* __restrict__ accT, const float* __restrict__ bias,
                                 float* __restrict__ out, int N) {
    __shared__ float tile[32][33];
    int j0 = blockIdx.x * 32;
    int tx = threadIdx.x;
    int ty = threadIdx.y;
    if (j0 + ty < N) tile[ty][tx] = accT[(long)(j0 + ty) * 32 + tx];
    __syncthreads();
    if (j0 + tx < N) out[ty * (long)N + j0 + tx] = tile[tx][ty] + bias[j0 + tx];
}

__global__ void edge_direct_kernel(const float* __restrict__ x, const float* __restrict__ values,
                                   const int* __restrict__ src, const int* __restrict__ dst,
                                   float* __restrict__ out, int nnz, int N_IN, int N_OUT) {
    int tid = blockIdx.x * blockDim.x + threadIdx.x;
    int lane_b = tid & 31;
    int e0 = tid >> 5;
    int estride = (gridDim.x * blockDim.x) >> 5;
    for (int e = e0; e < nnz; e += estride) {
        atomicAdd(&out[(long)lane_b * N_OUT + dst[e]],
                  values[e] * x[(long)lane_b * N_IN + src[e]]);
    }
}

__global__ void init_out_bias_kernel(float* __restrict__ out, const float* __restrict__ bias,
                                     int N_OUT, int B) {
    long i = (long)blockIdx.x * blockDim.x + threadIdx.x;
    if (i < (long)N_OUT * B) out[i] = bias[i % N_OUT];
}

extern "C" void kernel_launch(void* const* d_in, const int* in_sizes, int n_in,
                              void* d_out, int out_size, void* d_ws, size_t ws_size,
                              hipStream_t stream) {
    const float* x      = (const float*)d_in[0];
    const float* values = (const float*)d_in[1];
    const float* bias   = (const float*)d_in[2];
    const int*   idx    = (const int*)d_in[3];

    const int NNZ   = in_sizes[1];
    const int N_OUT = in_sizes[2];
    const int B     = out_size / N_OUT;
    const int N_IN  = in_sizes[0] / B;

    const int* src = idx;
    const int* dst = idx + NNZ;
    float* out = (float*)d_out;

    const int nchunk = (N_OUT + CH - 1) >> CH_LOG;

    const size_t xT_b     = (size_t)N_IN * 32 * sizeof(float);
    const size_t full_b   = (size_t)NNZ * sizeof(uint2);
    const size_t counts_b = (size_t)nchunk * sizeof(int);
    const size_t offs_b   = (size_t)(nchunk + 1) * sizeof(int);
    const size_t need_full = xT_b + full_b + counts_b + offs_b;

    const bool shape_ok = (B == 32) && (N_IN < (1 << PACK_SHIFT)) && (nchunk <= 4096) && (NNZ > 0);

    if (shape_ok && ws_size >= need_full) {
        char* p = (char*)d_ws;
        float* xT = (float*)p;       p += xT_b;
        uint2* binned = (uint2*)p;   p += full_b;
        int* counts = (int*)p;       p += counts_b;
        int* offsets = (int*)p;

        {
            dim3 blk(32, 32);
            xpose_in_kernel<<<(N_IN + 31) / 32, blk, 0, stream>>>(x, xT, N_IN);
        }
        hipMemsetAsync(counts, 0, counts_b, stream);
        count_kernel<<<512, 256, nchunk * sizeof(int), stream>>>(dst, counts, NNZ, nchunk);
        scan_kernel<<<1, 256, 0, stream>>>(counts, offsets, nchunk);
        scatter_full_kernel<<<1024, 256, 0, stream>>>(src, dst, values, counts, binned, NNZ);
        gather_chunk_kernel<<<nchunk, 256, 0, stream>>>(binned, offsets, xT, bias, out, N_OUT);
    } else if (B == 32 && ws_size >= xT_b + (size_t)N_OUT * 32 * sizeof(float)) {
        // round-1 fallback: global atomics into accT
        float* xT = (float*)d_ws;
        float* accT = (float*)((char*)d_ws + xT_b);
        dim3 blk(32, 32);
        xpose_in_kernel<<<(N_IN + 31) / 32, blk, 0, stream>>>(x, xT, N_IN);
        hipMemsetAsync(accT, 0, (size_t)N_OUT * 32 * sizeof(float), stream);
        edge_kernel<<<4096, 256, 0, stream>>>(xT, values, src, dst, accT, NNZ);
        xpose_out_kernel<<<(N_OUT + 31) / 32, blk, 0, stream>>>(accT, bias, out, N_OUT);
    } else {
        long total = (long)N_OUT * B;
        init_out_bias_kernel<<<(int)((total + 255) / 256), 256, 0, stream>>>(out, bias, N_OUT, B);
        edge_direct_kernel<<<4096, 256, 0, stream>>>(x, values, src, dst, out, NNZ, N_IN, N_OUT);
    }
}

// Round 4
// 882.950 us; speedup vs baseline: 1.2623x; 1.2520x over previous
//
#include <hip/hip_runtime.h>

// SparseLinear: out[b, j] = sum_{e: dst[e]==j} values[e] * x[b, src[e]] + bias[j]
// Inputs: x f32 (B,N_IN,1) | values f32 (NNZ,) | bias f32 (N_OUT,1)
//         indices i32 (2,NNZ) row0=src row1=dst | n_out scalar
// Output: f32 (B, N_OUT, 1)
//
// Pipeline: transpose x -> count per dst-chunk (padded counters) -> scan ->
// scatter into chunk bins (padded cursors) -> per-chunk LDS accumulate.
// Round-4: gather is lane-per-edge (structural MLP: coalesced record load +
// 8 named float4 row loads per lane); cursors/counters padded to 64B lines.

#define CH_LOG 6
#define CH 64           // dst nodes per chunk
#define PACK_SHIFT 20   // src in bits [0,20), dst-local in [20,26)
#define SRC_MASK ((1u << PACK_SHIFT) - 1u)

// ---------- transpose x (B=32, N) -> xT (N, 32) ----------
__global__ void xpose_in_kernel(const float* __restrict__ x, float* __restrict__ xT, int N) {
    __shared__ float tile[32][33];
    int n0 = blockIdx.x * 32;
    int tx = threadIdx.x;
    int ty = threadIdx.y;
    if (n0 + tx < N) tile[ty][tx] = x[ty * (long)N + n0 + tx];
    __syncthreads();
    if (n0 + ty < N) xT[(long)(n0 + ty) * 32 + tx] = tile[tx][ty];
}

// ---------- pass 1: per-chunk edge counts (padded global counters) ----------
__global__ void count_kernel(const int* __restrict__ dst, int* __restrict__ counts_pad,
                             int nnz, int nchunk, int cpad) {
    extern __shared__ int hist[];
    for (int i = threadIdx.x; i < nchunk; i += blockDim.x) hist[i] = 0;
    __syncthreads();
    int tid = blockIdx.x * blockDim.x + threadIdx.x;
    int nthreads = gridDim.x * blockDim.x;
    int nvec = nnz >> 2;
    const int4* dst4 = (const int4*)dst;
    for (int i = tid; i < nvec; i += nthreads) {
        int4 d = dst4[i];
        atomicAdd(&hist[d.x >> CH_LOG], 1);
        atomicAdd(&hist[d.y >> CH_LOG], 1);
        atomicAdd(&hist[d.z >> CH_LOG], 1);
        atomicAdd(&hist[d.w >> CH_LOG], 1);
    }
    for (int e = (nvec << 2) + tid; e < nnz; e += nthreads)
        atomicAdd(&hist[dst[e] >> CH_LOG], 1);
    __syncthreads();
    for (int i = threadIdx.x; i < nchunk; i += blockDim.x) {
        int h = hist[i];
        if (h) atomicAdd(&counts_pad[i * cpad], h);
    }
}

// ---------- pass 1b: exclusive scan; counts_pad becomes running cursors ----------
// single block, 256 threads, nchunk <= 4096
__global__ void scan_kernel(int* __restrict__ counts_pad, int* __restrict__ offsets,
                            int nchunk, int cpad) {
    __shared__ int wave_sums[4];
    int tid = threadIdx.x;
    int items = (nchunk + 255) >> 8;   // <= 16
    int base = tid * items;
    int local[16];
    int sum = 0;
    for (int k = 0; k < items; ++k) {
        int idx = base + k;
        int c = (idx < nchunk) ? counts_pad[idx * cpad] : 0;
        local[k] = sum;
        sum += c;
    }
    int lane = tid & 63, wid = tid >> 6;
    int inc = sum;
    for (int d = 1; d < 64; d <<= 1) {
        int n = __shfl_up(inc, d, 64);
        if (lane >= d) inc += n;
    }
    if (lane == 63) wave_sums[wid] = inc;
    __syncthreads();
    if (tid == 0) {
        int s = 0;
        for (int w = 0; w < 4; ++w) { int t = wave_sums[w]; wave_sums[w] = s; s += t; }
    }
    __syncthreads();
    int excl = inc - sum + wave_sums[wid];
    for (int k = 0; k < items; ++k) {
        int idx = base + k;
        if (idx < nchunk) {
            int off = excl + local[k];
            offsets[idx] = off;
            counts_pad[idx * cpad] = off;   // running cursor for scatter
        }
    }
    if (tid == 255) offsets[nchunk] = excl + sum;
}

// ---------- pass 2: scatter edges into chunk bins (padded cursors, 4-wide) ----------
__global__ void scatter_full_kernel(const int* __restrict__ src, const int* __restrict__ dst,
                                    const float* __restrict__ val, int* __restrict__ cursors_pad,
                                    uint2* __restrict__ binned, int nnz, int cpad) {
    int tid = blockIdx.x * blockDim.x + threadIdx.x;
    int nthreads = gridDim.x * blockDim.x;
    int nvec = nnz >> 2;
    const int4* src4 = (const int4*)src;
    const int4* dst4 = (const int4*)dst;
    const float4* val4 = (const float4*)val;
    for (int i = tid; i < nvec; i += nthreads) {
        int4 d = dst4[i];
        int4 s = src4[i];
        float4 v = val4[i];
        int p0 = atomicAdd(&cursors_pad[(d.x >> CH_LOG) * cpad], 1);
        int p1 = atomicAdd(&cursors_pad[(d.y >> CH_LOG) * cpad], 1);
        int p2 = atomicAdd(&cursors_pad[(d.z >> CH_LOG) * cpad], 1);
        int p3 = atomicAdd(&cursors_pad[(d.w >> CH_LOG) * cpad], 1);
        binned[p0] = make_uint2((unsigned)s.x | ((unsigned)(d.x & (CH - 1)) << PACK_SHIFT), __float_as_uint(v.x));
        binned[p1] = make_uint2((unsigned)s.y | ((unsigned)(d.y & (CH - 1)) << PACK_SHIFT), __float_as_uint(v.y));
        binned[p2] = make_uint2((unsigned)s.z | ((unsigned)(d.z & (CH - 1)) << PACK_SHIFT), __float_as_uint(v.z));
        binned[p3] = make_uint2((unsigned)s.w | ((unsigned)(d.w & (CH - 1)) << PACK_SHIFT), __float_as_uint(v.w));
    }
    for (int e = (nvec << 2) + tid; e < nnz; e += nthreads) {
        int d = dst[e];
        int p = atomicAdd(&cursors_pad[(d >> CH_LOG) * cpad], 1);
        binned[p] = make_uint2((unsigned)src[e] | ((unsigned)(d & (CH - 1)) << PACK_SHIFT),
                               __float_as_uint(val[e]));
    }
}

// ---------- pass 3: per-chunk gather, LANE-PER-EDGE, LDS accumulate ----------
__global__ __launch_bounds__(256) void gather_chunk_kernel(
        const uint2* __restrict__ binned, const int* __restrict__ offsets,
        const float* __restrict__ xT, const float* __restrict__ bias,
        float* __restrict__ out, int n_out) {
    __shared__ float acc[CH * 33];   // bank (jl+b)%32: random jl -> ~2-way
    int c = blockIdx.x;
    int j0 = c << CH_LOG;
    for (int i = threadIdx.x; i < CH * 33; i += blockDim.x) acc[i] = 0.0f;
    __syncthreads();

    int beg = offsets[c], end = offsets[c + 1];
    // each lane owns one edge per iteration: coalesced record load,
    // 8 independent float4 loads of the full xT row, 32 LDS atomics.
    for (int e = beg + threadIdx.x; e < end; e += 256) {
        uint2 r = binned[e];
        int s = (int)(r.x & SRC_MASK);
        int jl = (int)(r.x >> PACK_SHIFT);
        float v = __uint_as_float(r.y);
        const float4* row = (const float4*)(xT + (long)s * 32);
        float4 x0 = row[0];
        float4 x1 = row[1];
        float4 x2 = row[2];
        float4 x3 = row[3];
        float4 x4 = row[4];
        float4 x5 = row[5];
        float4 x6 = row[6];
        float4 x7 = row[7];
        float* a = &acc[jl * 33];
        atomicAdd(&a[0],  v * x0.x); atomicAdd(&a[1],  v * x0.y);
        atomicAdd(&a[2],  v * x0.z); atomicAdd(&a[3],  v * x0.w);
        atomicAdd(&a[4],  v * x1.x); atomicAdd(&a[5],  v * x1.y);
        atomicAdd(&a[6],  v * x1.z); atomicAdd(&a[7],  v * x1.w);
        atomicAdd(&a[8],  v * x2.x); atomicAdd(&a[9],  v * x2.y);
        atomicAdd(&a[10], v * x2.z); atomicAdd(&a[11], v * x2.w);
        atomicAdd(&a[12], v * x3.x); atomicAdd(&a[13], v * x3.y);
        atomicAdd(&a[14], v * x3.z); atomicAdd(&a[15], v * x3.w);
        atomicAdd(&a[16], v * x4.x); atomicAdd(&a[17], v * x4.y);
        atomicAdd(&a[18], v * x4.z); atomicAdd(&a[19], v * x4.w);
        atomicAdd(&a[20], v * x5.x); atomicAdd(&a[21], v * x5.y);
        atomicAdd(&a[22], v * x5.z); atomicAdd(&a[23], v * x5.w);
        atomicAdd(&a[24], v * x6.x); atomicAdd(&a[25], v * x6.y);
        atomicAdd(&a[26], v * x6.z); atomicAdd(&a[27], v * x6.w);
        atomicAdd(&a[28], v * x7.x); atomicAdd(&a[29], v * x7.y);
        atomicAdd(&a[30], v * x7.z); atomicAdd(&a[31], v * x7.w);
    }
    __syncthreads();

    for (int i = threadIdx.x; i < CH * 32; i += blockDim.x) {
        int bb = i >> CH_LOG;
        int jl = i & (CH - 1);
        int j = j0 + jl;
        if (j < n_out) out[bb * n_out + j] = acc[jl * 33 + bb] + bias[j];
    }
}

// ================= fallback kernels =================
__global__ void edge_kernel(const float* __restrict__ xT, const float* __restrict__ values,
                            const int* __restrict__ src, const int* __restrict__ dst,
                            float* __restrict__ accT, int nnz) {
    int tid = blockIdx.x * blockDim.x + threadIdx.x;
    int lane_b = tid & 31;
    int e0 = tid >> 5;
    int estride = (gridDim.x * blockDim.x) >> 5;
    for (int e = e0; e < nnz; e += estride) {
        atomicAdd(&accT[(long)dst[e] * 32 + lane_b], values[e] * xT[(long)src[e] * 32 + lane_b]);
    }
}

__global__ void xpose_out_kernel(const float* __restrict__ accT, const float* __restrict__ bias,
                                 float* __restrict__ out, int N) {
    __shared__ float tile[32][33];
    int j0 = blockIdx.x * 32;
    int tx = threadIdx.x;
    int ty = threadIdx.y;
    if (j0 + ty < N) tile[ty][tx] = accT[(long)(j0 + ty) * 32 + tx];
    __syncthreads();
    if (j0 + tx < N) out[ty * (long)N + j0 + tx] = tile[tx][ty] + bias[j0 + tx];
}

__global__ void edge_direct_kernel(const float* __restrict__ x, const float* __restrict__ values,
                                   const int* __restrict__ src, const int* __restrict__ dst,
                                   float* __restrict__ out, int nnz, int N_IN, int N_OUT) {
    int tid = blockIdx.x * blockDim.x + threadIdx.x;
    int lane_b = tid & 31;
    int e0 = tid >> 5;
    int estride = (gridDim.x * blockDim.x) >> 5;
    for (int e = e0; e < nnz; e += estride) {
        atomicAdd(&out[(long)lane_b * N_OUT + dst[e]],
                  values[e] * x[(long)lane_b * N_IN + src[e]]);
    }
}

__global__ void init_out_bias_kernel(float* __restrict__ out, const float* __restrict__ bias,
                                     int N_OUT, int B) {
    long i = (long)blockIdx.x * blockDim.x + threadIdx.x;
    if (i < (long)N_OUT * B) out[i] = bias[i % N_OUT];
}

extern "C" void kernel_launch(void* const* d_in, const int* in_sizes, int n_in,
                              void* d_out, int out_size, void* d_ws, size_t ws_size,
                              hipStream_t stream) {
    const float* x      = (const float*)d_in[0];
    const float* values = (const float*)d_in[1];
    const float* bias   = (const float*)d_in[2];
    const int*   idx    = (const int*)d_in[3];

    const int NNZ   = in_sizes[1];
    const int N_OUT = in_sizes[2];
    const int B     = out_size / N_OUT;
    const int N_IN  = in_sizes[0] / B;

    const int* src = idx;
    const int* dst = idx + NNZ;
    float* out = (float*)d_out;

    const int nchunk = (N_OUT + CH - 1) >> CH_LOG;

    const size_t xT_b   = (size_t)N_IN * 32 * sizeof(float);
    const size_t full_b = (size_t)NNZ * sizeof(uint2);
    const size_t offs_b = (size_t)(nchunk + 1) * sizeof(int);

    const bool shape_ok = (B == 32) && (N_IN < (1 << PACK_SHIFT)) && (nchunk <= 4096) && (NNZ > 0);

    // pick cursor padding: 16 ints (one per 64B line) if it fits, else 1
    int cpad = 16;
    size_t counts_b = (size_t)nchunk * cpad * sizeof(int);
    if (shape_ok && ws_size < xT_b + full_b + offs_b + counts_b) {
        cpad = 1;
        counts_b = (size_t)nchunk * sizeof(int);
    }
    const size_t need_full = xT_b + full_b + offs_b + counts_b;

    if (shape_ok && ws_size >= need_full) {
        char* p = (char*)d_ws;
        float* xT = (float*)p;       p += xT_b;
        uint2* binned = (uint2*)p;   p += full_b;
        int* offsets = (int*)p;      p += offs_b;
        int* counts_pad = (int*)p;

        {
            dim3 blk(32, 32);
            xpose_in_kernel<<<(N_IN + 31) / 32, blk, 0, stream>>>(x, xT, N_IN);
        }
        hipMemsetAsync(counts_pad, 0, counts_b, stream);
        count_kernel<<<512, 256, nchunk * sizeof(int), stream>>>(dst, counts_pad, NNZ, nchunk, cpad);
        scan_kernel<<<1, 256, 0, stream>>>(counts_pad, offsets, nchunk, cpad);
        scatter_full_kernel<<<1024, 256, 0, stream>>>(src, dst, values, counts_pad, binned, NNZ, cpad);
        gather_chunk_kernel<<<nchunk, 256, 0, stream>>>(binned, offsets, xT, bias, out, N_OUT);
    } else if (B == 32 && ws_size >= xT_b + (size_t)N_OUT * 32 * sizeof(float)) {
        // round-1 fallback: global atomics into accT
        float* xT = (float*)d_ws;
        float* accT = (float*)((char*)d_ws + xT_b);
        dim3 blk(32, 32);
        xpose_in_kernel<<<(N_IN + 31) / 32, blk, 0, stream>>>(x, xT, N_IN);
        hipMemsetAsync(accT, 0, (size_t)N_OUT * 32 * sizeof(float), stream);
        edge_kernel<<<4096, 256, 0, stream>>>(xT, values, src, dst, accT, NNZ);
        xpose_out_kernel<<<(N_OUT + 31) / 32, blk, 0, stream>>>(accT, bias, out, N_OUT);
    } else {
        long total = (long)N_OUT * B;
        init_out_bias_kernel<<<(int)((total + 255) / 256), 256, 0, stream>>>(out, bias, N_OUT, B);
        edge_direct_kernel<<<4096, 256, 0, stream>>>(x, values, src, dst, out, NNZ, N_IN, N_OUT);
    }
}

// Round 5
// 851.567 us; speedup vs baseline: 1.3088x; 1.0369x over previous
//
#include <hip/hip_runtime.h>

// SparseLinear: out[b, j] = sum_{e: dst[e]==j} values[e] * x[b, src[e]] + bias[j]
// Inputs: x f32 (B,N_IN,1) | values f32 (NNZ,) | bias f32 (N_OUT,1)
//         indices i32 (2,NNZ) row0=src row1=dst | n_out scalar
// Output: f32 (B, N_OUT, 1)
//
// Pipeline: transpose x -> count per dst-chunk -> scan -> scatter into chunk
// bins -> per-chunk LDS accumulate.
// Round-5: gather = 1024-thread blocks, 4 lanes per edge (2 float4 / lane:
// intra-instruction line coalescing + 16-wave blocks for TLP latency hiding;
// round-4 lane-per-edge was compiler-serialized at VGPR=20, 64 divergent
// lines/instr). Cursors padded to 128B L2 lines (cpad=32).

#define CH_LOG 6
#define CH 64           // dst nodes per chunk
#define PACK_SHIFT 20   // src in bits [0,20), dst-local in [20,26)
#define SRC_MASK ((1u << PACK_SHIFT) - 1u)

// ---------- transpose x (B=32, N) -> xT (N, 32) ----------
__global__ void xpose_in_kernel(const float* __restrict__ x, float* __restrict__ xT, int N) {
    __shared__ float tile[32][33];
    int n0 = blockIdx.x * 32;
    int tx = threadIdx.x;
    int ty = threadIdx.y;
    if (n0 + tx < N) tile[ty][tx] = x[ty * (long)N + n0 + tx];
    __syncthreads();
    if (n0 + ty < N) xT[(long)(n0 + ty) * 32 + tx] = tile[tx][ty];
}

// ---------- pass 1: per-chunk edge counts (padded global counters) ----------
__global__ void count_kernel(const int* __restrict__ dst, int* __restrict__ counts_pad,
                             int nnz, int nchunk, int cpad) {
    extern __shared__ int hist[];
    for (int i = threadIdx.x; i < nchunk; i += blockDim.x) hist[i] = 0;
    __syncthreads();
    int tid = blockIdx.x * blockDim.x + threadIdx.x;
    int nthreads = gridDim.x * blockDim.x;
    int nvec = nnz >> 2;
    const int4* dst4 = (const int4*)dst;
    for (int i = tid; i < nvec; i += nthreads) {
        int4 d = dst4[i];
        atomicAdd(&hist[d.x >> CH_LOG], 1);
        atomicAdd(&hist[d.y >> CH_LOG], 1);
        atomicAdd(&hist[d.z >> CH_LOG], 1);
        atomicAdd(&hist[d.w >> CH_LOG], 1);
    }
    for (int e = (nvec << 2) + tid; e < nnz; e += nthreads)
        atomicAdd(&hist[dst[e] >> CH_LOG], 1);
    __syncthreads();
    for (int i = threadIdx.x; i < nchunk; i += blockDim.x) {
        int h = hist[i];
        if (h) atomicAdd(&counts_pad[i * cpad], h);
    }
}

// ---------- pass 1b: exclusive scan; counts_pad becomes running cursors ----------
// single block, 256 threads, nchunk <= 4096
__global__ void scan_kernel(int* __restrict__ counts_pad, int* __restrict__ offsets,
                            int nchunk, int cpad) {
    __shared__ int wave_sums[4];
    int tid = threadIdx.x;
    int items = (nchunk + 255) >> 8;   // <= 16
    int base = tid * items;
    int local[16];
    int sum = 0;
    for (int k = 0; k < items; ++k) {
        int idx = base + k;
        int c = (idx < nchunk) ? counts_pad[idx * cpad] : 0;
        local[k] = sum;
        sum += c;
    }
    int lane = tid & 63, wid = tid >> 6;
    int inc = sum;
    for (int d = 1; d < 64; d <<= 1) {
        int n = __shfl_up(inc, d, 64);
        if (lane >= d) inc += n;
    }
    if (lane == 63) wave_sums[wid] = inc;
    __syncthreads();
    if (tid == 0) {
        int s = 0;
        for (int w = 0; w < 4; ++w) { int t = wave_sums[w]; wave_sums[w] = s; s += t; }
    }
    __syncthreads();
    int excl = inc - sum + wave_sums[wid];
    for (int k = 0; k < items; ++k) {
        int idx = base + k;
        if (idx < nchunk) {
            int off = excl + local[k];
            offsets[idx] = off;
            counts_pad[idx * cpad] = off;   // running cursor for scatter
        }
    }
    if (tid == 255) offsets[nchunk] = excl + sum;
}

// ---------- pass 2: scatter edges into chunk bins (padded cursors) ----------
__global__ void scatter_full_kernel(const int* __restrict__ src, const int* __restrict__ dst,
                                    const float* __restrict__ val, int* __restrict__ cursors_pad,
                                    uint2* __restrict__ binned, int nnz, int cpad) {
    int tid = blockIdx.x * blockDim.x + threadIdx.x;
    int nthreads = gridDim.x * blockDim.x;
    int nvec = nnz >> 2;
    const int4* src4 = (const int4*)src;
    const int4* dst4 = (const int4*)dst;
    const float4* val4 = (const float4*)val;
    for (int i = tid; i < nvec; i += nthreads) {
        int4 d = dst4[i];
        int4 s = src4[i];
        float4 v = val4[i];
        int p0 = atomicAdd(&cursors_pad[(d.x >> CH_LOG) * cpad], 1);
        int p1 = atomicAdd(&cursors_pad[(d.y >> CH_LOG) * cpad], 1);
        int p2 = atomicAdd(&cursors_pad[(d.z >> CH_LOG) * cpad], 1);
        int p3 = atomicAdd(&cursors_pad[(d.w >> CH_LOG) * cpad], 1);
        binned[p0] = make_uint2((unsigned)s.x | ((unsigned)(d.x & (CH - 1)) << PACK_SHIFT), __float_as_uint(v.x));
        binned[p1] = make_uint2((unsigned)s.y | ((unsigned)(d.y & (CH - 1)) << PACK_SHIFT), __float_as_uint(v.y));
        binned[p2] = make_uint2((unsigned)s.z | ((unsigned)(d.z & (CH - 1)) << PACK_SHIFT), __float_as_uint(v.z));
        binned[p3] = make_uint2((unsigned)s.w | ((unsigned)(d.w & (CH - 1)) << PACK_SHIFT), __float_as_uint(v.w));
    }
    for (int e = (nvec << 2) + tid; e < nnz; e += nthreads) {
        int d = dst[e];
        int p = atomicAdd(&cursors_pad[(d >> CH_LOG) * cpad], 1);
        binned[p] = make_uint2((unsigned)src[e] | ((unsigned)(d & (CH - 1)) << PACK_SHIFT),
                               __float_as_uint(val[e]));
    }
}

// ---------- pass 3: per-chunk gather, 4 LANES PER EDGE, 1024 threads ----------
__global__ __launch_bounds__(1024) void gather_chunk_kernel(
        const uint2* __restrict__ binned, const int* __restrict__ offsets,
        const float* __restrict__ xT, const float* __restrict__ bias,
        float* __restrict__ out, int n_out) {
    __shared__ float acc[CH * 33];   // bank (jl+b)%32: random jl -> ~2-way
    int c = blockIdx.x;
    int j0 = c << CH_LOG;
    for (int i = threadIdx.x; i < CH * 33; i += 1024) acc[i] = 0.0f;
    __syncthreads();

    int beg = offsets[c], end = offsets[c + 1];
    int slot = threadIdx.x >> 2;   // 256 edge slots
    int sub  = threadIdx.x & 3;    // which 32B of the 128B row
    for (int e = beg + slot; e < end; e += 256) {
        uint2 r = binned[e];       // 4 lanes same record -> 1 line req
        int s  = (int)(r.x & SRC_MASK);
        int jl = (int)(r.x >> PACK_SHIFT);
        float v = __uint_as_float(r.y);
        const float4* row = (const float4*)(xT + ((long)s << 5)) + (sub << 1);
        float4 xa = row[0];
        float4 xb = row[1];
        float* a = &acc[jl * 33 + (sub << 3)];
        atomicAdd(&a[0], v * xa.x); atomicAdd(&a[1], v * xa.y);
        atomicAdd(&a[2], v * xa.z); atomicAdd(&a[3], v * xa.w);
        atomicAdd(&a[4], v * xb.x); atomicAdd(&a[5], v * xb.y);
        atomicAdd(&a[6], v * xb.z); atomicAdd(&a[7], v * xb.w);
    }
    __syncthreads();

    for (int i = threadIdx.x; i < CH * 32; i += 1024) {
        int bb = i >> CH_LOG;
        int jl = i & (CH - 1);
        int j = j0 + jl;
        if (j < n_out) out[bb * n_out + j] = acc[jl * 33 + bb] + bias[j];
    }
}

// ================= fallback kernels =================
__global__ void edge_kernel(const float* __restrict__ xT, const float* __restrict__ values,
                            const int* __restrict__ src, const int* __restrict__ dst,
                            float* __restrict__ accT, int nnz) {
    int tid = blockIdx.x * blockDim.x + threadIdx.x;
    int lane_b = tid & 31;
    int e0 = tid >> 5;
    int estride = (gridDim.x * blockDim.x) >> 5;
    for (int e = e0; e < nnz; e += estride) {
        atomicAdd(&accT[(long)dst[e] * 32 + lane_b], values[e] * xT[(long)src[e] * 32 + lane_b]);
    }
}

__global__ void xpose_out_kernel(const float* __restrict__ accT, const float* __restrict__ bias,
                                 float* __restrict__ out, int N) {
    __shared__ float tile[32][33];
    int j0 = blockIdx.x * 32;
    int tx = threadIdx.x;
    int ty = threadIdx.y;
    if (j0 + ty < N) tile[ty][tx] = accT[(long)(j0 + ty) * 32 + tx];
    __syncthreads();
    if (j0 + tx < N) out[ty * (long)N + j0 + tx] = tile[tx][ty] + bias[j0 + tx];
}

__global__ void edge_direct_kernel(const float* __restrict__ x, const float* __restrict__ values,
                                   const int* __restrict__ src, const int* __restrict__ dst,
                                   float* __restrict__ out, int nnz, int N_IN, int N_OUT) {
    int tid = blockIdx.x * blockDim.x + threadIdx.x;
    int lane_b = tid & 31;
    int e0 = tid >> 5;
    int estride = (gridDim.x * blockDim.x) >> 5;
    for (int e = e0; e < nnz; e += estride) {
        atomicAdd(&out[(long)lane_b * N_OUT + dst[e]],
                  values[e] * x[(long)lane_b * N_IN + src[e]]);
    }
}

__global__ void init_out_bias_kernel(float* __restrict__ out, const float* __restrict__ bias,
                                     int N_OUT, int B) {
    long i = (long)blockIdx.x * blockDim.x + threadIdx.x;
    if (i < (long)N_OUT * B) out[i] = bias[i % N_OUT];
}

extern "C" void kernel_launch(void* const* d_in, const int* in_sizes, int n_in,
                              void* d_out, int out_size, void* d_ws, size_t ws_size,
                              hipStream_t stream) {
    const float* x      = (const float*)d_in[0];
    const float* values = (const float*)d_in[1];
    const float* bias   = (const float*)d_in[2];
    const int*   idx    = (const int*)d_in[3];

    const int NNZ   = in_sizes[1];
    const int N_OUT = in_sizes[2];
    const int B     = out_size / N_OUT;
    const int N_IN  = in_sizes[0] / B;

    const int* src = idx;
    const int* dst = idx + NNZ;
    float* out = (float*)d_out;

    const int nchunk = (N_OUT + CH - 1) >> CH_LOG;

    const size_t xT_b   = (size_t)N_IN * 32 * sizeof(float);
    const size_t full_b = (size_t)NNZ * sizeof(uint2);
    const size_t offs_b = (size_t)(nchunk + 1) * sizeof(int);

    const bool shape_ok = (B == 32) && (N_IN < (1 << PACK_SHIFT)) && (nchunk <= 4096) && (NNZ > 0);

    // cursor padding: 32 ints (one per 128B L2 line) if it fits, else 16, else 1
    int cpad = 32;
    size_t counts_b = (size_t)nchunk * cpad * sizeof(int);
    if (shape_ok && ws_size < xT_b + full_b + offs_b + counts_b) {
        cpad = 16;
        counts_b = (size_t)nchunk * cpad * sizeof(int);
    }
    if (shape_ok && ws_size < xT_b + full_b + offs_b + counts_b) {
        cpad = 1;
        counts_b = (size_t)nchunk * sizeof(int);
    }
    const size_t need_full = xT_b + full_b + offs_b + counts_b;

    if (shape_ok && ws_size >= need_full) {
        char* p = (char*)d_ws;
        float* xT = (float*)p;       p += xT_b;
        uint2* binned = (uint2*)p;   p += full_b;
        int* offsets = (int*)p;      p += offs_b;
        int* counts_pad = (int*)p;

        {
            dim3 blk(32, 32);
            xpose_in_kernel<<<(N_IN + 31) / 32, blk, 0, stream>>>(x, xT, N_IN);
        }
        hipMemsetAsync(counts_pad, 0, counts_b, stream);
        count_kernel<<<512, 256, nchunk * sizeof(int), stream>>>(dst, counts_pad, NNZ, nchunk, cpad);
        scan_kernel<<<1, 256, 0, stream>>>(counts_pad, offsets, nchunk, cpad);
        scatter_full_kernel<<<1024, 256, 0, stream>>>(src, dst, values, counts_pad, binned, NNZ, cpad);
        gather_chunk_kernel<<<nchunk, 1024, 0, stream>>>(binned, offsets, xT, bias, out, N_OUT);
    } else if (B == 32 && ws_size >= xT_b + (size_t)N_OUT * 32 * sizeof(float)) {
        // round-1 fallback: global atomics into accT
        float* xT = (float*)d_ws;
        float* accT = (float*)((char*)d_ws + xT_b);
        dim3 blk(32, 32);
        xpose_in_kernel<<<(N_IN + 31) / 32, blk, 0, stream>>>(x, xT, N_IN);
        hipMemsetAsync(accT, 0, (size_t)N_OUT * 32 * sizeof(float), stream);
        edge_kernel<<<4096, 256, 0, stream>>>(xT, values, src, dst, accT, NNZ);
        xpose_out_kernel<<<(N_OUT + 31) / 32, blk, 0, stream>>>(accT, bias, out, N_OUT);
    } else {
        long total = (long)N_OUT * B;
        init_out_bias_kernel<<<(int)((total + 255) / 256), 256, 0, stream>>>(out, bias, N_OUT, B);
        edge_direct_kernel<<<4096, 256, 0, stream>>>(x, values, src, dst, out, NNZ, N_IN, N_OUT);
    }
}

// Round 6
// 583.940 us; speedup vs baseline: 1.9087x; 1.4583x over previous
//
#include <hip/hip_runtime.h>

// SparseLinear: out[b, j] = sum_{e: dst[e]==j} values[e] * x[b, src[e]] + bias[j]
// Inputs: x f32 (B,N_IN,1) | values f32 (NNZ,) | bias f32 (N_OUT,1)
//         indices i32 (2,NNZ) row0=src row1=dst | n_out scalar
// Output: f32 (B, N_OUT, 1)
//
// Round-6: per-dst binning + register-accumulation gather (NO LDS atomics).
// Rounds 2-5 showed gather invariant ~600us across 3 access structures ->
// LDS f32-atomic throughput hypothesis (~0.3 lane-op/cyc/CU). This version
// has zero atomics in the accumulation path.

#define TJ 64   // output columns per gather block

// ---------- transpose x (B=32, N) -> xT (N, 32) ----------
__global__ void xpose_in_kernel(const float* __restrict__ x, float* __restrict__ xT, int N) {
    __shared__ float tile[32][33];
    int n0 = blockIdx.x * 32;
    int tx = threadIdx.x;
    int ty = threadIdx.y;
    if (n0 + tx < N) tile[ty][tx] = x[ty * (long)N + n0 + tx];
    __syncthreads();
    if (n0 + ty < N) xT[(long)(n0 + ty) * 32 + tx] = tile[tx][ty];
}

// ---------- count per-dst (padded global counters) ----------
__global__ void count_kernel(const int* __restrict__ dst, int* __restrict__ cnt_pad,
                             int nnz, int cpad) {
    int tid = blockIdx.x * blockDim.x + threadIdx.x;
    int nth = gridDim.x * blockDim.x;
    int nvec = nnz >> 2;
    const int4* d4 = (const int4*)dst;
    for (int i = tid; i < nvec; i += nth) {
        int4 d = d4[i];
        atomicAdd(&cnt_pad[d.x * cpad], 1);
        atomicAdd(&cnt_pad[d.y * cpad], 1);
        atomicAdd(&cnt_pad[d.z * cpad], 1);
        atomicAdd(&cnt_pad[d.w * cpad], 1);
    }
    for (int e = (nvec << 2) + tid; e < nnz; e += nth)
        atomicAdd(&cnt_pad[dst[e] * cpad], 1);
}

// ---------- hierarchical exclusive scan over n bins (strided by cpad) ----------
// scanA: per-1024-segment exclusive scan in place; segment totals out.
__global__ __launch_bounds__(1024) void scanA_kernel(int* __restrict__ cnt_pad,
                                                     int* __restrict__ seg_total,
                                                     int n, int cpad) {
    __shared__ int wsum[16];
    int idx = blockIdx.x * 1024 + threadIdx.x;
    int v = (idx < n) ? cnt_pad[idx * cpad] : 0;
    int lane = threadIdx.x & 63, wid = threadIdx.x >> 6;
    int inc = v;
    for (int d = 1; d < 64; d <<= 1) {
        int t = __shfl_up(inc, d, 64);
        if (lane >= d) inc += t;
    }
    if (lane == 63) wsum[wid] = inc;
    __syncthreads();
    int base = 0;
    for (int w = 0; w < wid; ++w) base += wsum[w];
    if (idx < n) cnt_pad[idx * cpad] = base + inc - v;
    if (threadIdx.x == 1023) seg_total[blockIdx.x] = base + inc;
}

// scanB: single block exclusive scan of segment totals (nseg <= 1024)
__global__ __launch_bounds__(1024) void scanB_kernel(int* __restrict__ seg_total, int nseg) {
    __shared__ int wsum[16];
    int v = (threadIdx.x < nseg) ? seg_total[threadIdx.x] : 0;
    int lane = threadIdx.x & 63, wid = threadIdx.x >> 6;
    int inc = v;
    for (int d = 1; d < 64; d <<= 1) {
        int t = __shfl_up(inc, d, 64);
        if (lane >= d) inc += t;
    }
    if (lane == 63) wsum[wid] = inc;
    __syncthreads();
    int base = 0;
    for (int w = 0; w < wid; ++w) base += wsum[w];
    if (threadIdx.x < nseg) seg_total[threadIdx.x] = base + inc - v;
}

// scanC: add segment bases back
__global__ __launch_bounds__(1024) void scanC_kernel(int* __restrict__ cnt_pad,
                                                     const int* __restrict__ seg_total,
                                                     int n, int cpad) {
    int idx = blockIdx.x * 1024 + threadIdx.x;
    if (idx < n) cnt_pad[idx * cpad] += seg_total[blockIdx.x];
}

// ---------- scatter edges into per-dst bins: record = {src, val} ----------
__global__ void scatter_kernel(const int* __restrict__ src, const int* __restrict__ dst,
                               const float* __restrict__ val, int* __restrict__ cur_pad,
                               uint2* __restrict__ binned, int nnz, int cpad) {
    int tid = blockIdx.x * blockDim.x + threadIdx.x;
    int nth = gridDim.x * blockDim.x;
    int nvec = nnz >> 2;
    const int4* s4 = (const int4*)src;
    const int4* d4 = (const int4*)dst;
    const float4* v4 = (const float4*)val;
    for (int i = tid; i < nvec; i += nth) {
        int4 d = d4[i];
        int4 s = s4[i];
        float4 v = v4[i];
        int p0 = atomicAdd(&cur_pad[d.x * cpad], 1);
        int p1 = atomicAdd(&cur_pad[d.y * cpad], 1);
        int p2 = atomicAdd(&cur_pad[d.z * cpad], 1);
        int p3 = atomicAdd(&cur_pad[d.w * cpad], 1);
        binned[p0] = make_uint2((unsigned)s.x, __float_as_uint(v.x));
        binned[p1] = make_uint2((unsigned)s.y, __float_as_uint(v.y));
        binned[p2] = make_uint2((unsigned)s.z, __float_as_uint(v.z));
        binned[p3] = make_uint2((unsigned)s.w, __float_as_uint(v.w));
    }
    for (int e = (nvec << 2) + tid; e < nnz; e += nth) {
        int p = atomicAdd(&cur_pad[dst[e] * cpad], 1);
        binned[p] = make_uint2((unsigned)src[e], __float_as_uint(val[e]));
    }
}

// ---------- gather: block = TJ consecutive j; wave owns 16 j's in registers ----------
// After scatter, cur_pad[j] == offsets[j+1]; beg(j) = (j==0) ? 0 : cur_pad[j-1].
__global__ __launch_bounds__(256) void gather_dst_kernel(
        const uint2* __restrict__ binned, const int* __restrict__ cur_pad, int cpad,
        const float* __restrict__ xT, const float* __restrict__ bias,
        float* __restrict__ out, int n_out) {
    __shared__ float tile[TJ][33];
    int j0 = blockIdx.x * TJ;
    int wv = threadIdx.x >> 6;       // wave 0..3
    int lane = threadIdx.x & 63;
    int b = lane & 31;               // batch column
    int h = lane >> 5;               // edge parity
    int jlbase = wv * 16;

    float acc[16];
    int beg[16], cnt[16];
    int jfirst = j0 + jlbase;
    int e_prev = (jfirst > 0 && jfirst <= n_out) ? cur_pad[(jfirst - 1) * cpad] : 0;
    int maxc = 0;
#pragma unroll
    for (int k = 0; k < 16; ++k) {
        int j = jfirst + k;
        int e1 = (j < n_out) ? cur_pad[j * cpad] : e_prev;
        beg[k] = e_prev;
        cnt[k] = e1 - e_prev;
        maxc = max(maxc, cnt[k]);
        acc[k] = 0.0f;
        e_prev = e1;
    }

    int maxT = (maxc + 1) >> 1;
    for (int tt = 0; tt < maxT; ++tt) {
        int t = (tt << 1) | h;
#pragma unroll
        for (int k = 0; k < 16; ++k) {
            if (t < cnt[k]) {
                uint2 r = binned[beg[k] + t];                 // 2 records/line, broadcast
                float xv = xT[((int)r.x << 5) + b];           // 128B coalesced row
                acc[k] += __uint_as_float(r.y) * xv;
            }
        }
    }

#pragma unroll
    for (int k = 0; k < 16; ++k) {
        float a = acc[k] + __shfl_xor(acc[k], 32);            // combine edge parities
        if (h == 0) tile[jlbase + k][b] = a;                  // unique writer
    }
    __syncthreads();

    for (int i = threadIdx.x; i < TJ * 32; i += 256) {
        int bb = i >> 6;           // batch row (4 per pass)
        int jl = i & (TJ - 1);
        int j = j0 + jl;
        if (j < n_out) out[bb * n_out + j] = tile[jl][bb] + bias[j];
    }
}

// ================= fallback (round-1 path) =================
__global__ void edge_kernel(const float* __restrict__ xT, const float* __restrict__ values,
                            const int* __restrict__ src, const int* __restrict__ dst,
                            float* __restrict__ accT, int nnz) {
    int tid = blockIdx.x * blockDim.x + threadIdx.x;
    int lane_b = tid & 31;
    int e0 = tid >> 5;
    int estride = (gridDim.x * blockDim.x) >> 5;
    for (int e = e0; e < nnz; e += estride) {
        atomicAdd(&accT[(long)dst[e] * 32 + lane_b], values[e] * xT[(long)src[e] * 32 + lane_b]);
    }
}

__global__ void xpose_out_kernel(const float* __restrict__ accT, const float* __restrict__ bias,
                                 float* __restrict__ out, int N) {
    __shared__ float tile[32][33];
    int j0 = blockIdx.x * 32;
    int tx = threadIdx.x;
    int ty = threadIdx.y;
    if (j0 + ty < N) tile[ty][tx] = accT[(long)(j0 + ty) * 32 + tx];
    __syncthreads();
    if (j0 + tx < N) out[ty * (long)N + j0 + tx] = tile[tx][ty] + bias[j0 + tx];
}

__global__ void edge_direct_kernel(const float* __restrict__ x, const float* __restrict__ values,
                                   const int* __restrict__ src, const int* __restrict__ dst,
                                   float* __restrict__ out, int nnz, int N_IN, int N_OUT) {
    int tid = blockIdx.x * blockDim.x + threadIdx.x;
    int lane_b = tid & 31;
    int e0 = tid >> 5;
    int estride = (gridDim.x * blockDim.x) >> 5;
    for (int e = e0; e < nnz; e += estride) {
        atomicAdd(&out[(long)lane_b * N_OUT + dst[e]],
                  values[e] * x[(long)lane_b * N_IN + src[e]]);
    }
}

__global__ void init_out_bias_kernel(float* __restrict__ out, const float* __restrict__ bias,
                                     int N_OUT, int B) {
    long i = (long)blockIdx.x * blockDim.x + threadIdx.x;
    if (i < (long)N_OUT * B) out[i] = bias[i % N_OUT];
}

extern "C" void kernel_launch(void* const* d_in, const int* in_sizes, int n_in,
                              void* d_out, int out_size, void* d_ws, size_t ws_size,
                              hipStream_t stream) {
    const float* x      = (const float*)d_in[0];
    const float* values = (const float*)d_in[1];
    const float* bias   = (const float*)d_in[2];
    const int*   idx    = (const int*)d_in[3];

    const int NNZ   = in_sizes[1];
    const int N_OUT = in_sizes[2];
    const int B     = out_size / N_OUT;
    const int N_IN  = in_sizes[0] / B;

    const int* src = idx;
    const int* dst = idx + NNZ;
    float* out = (float*)d_out;

    const int nseg = (N_OUT + 1023) >> 10;

    const size_t xT_b   = (size_t)N_IN * 32 * sizeof(float);
    const size_t bin_b  = (size_t)NNZ * sizeof(uint2);
    const size_t seg_b  = (size_t)nseg * sizeof(int);

    const bool shape_ok = (B == 32) && (NNZ > 0) && (nseg <= 1024);

    // cursor padding ladder: 8 -> 4 -> 2 -> 1 ints per counter
    int cpad = 8;
    size_t cnt_b = (size_t)N_OUT * cpad * sizeof(int);
    while (cpad > 1 && ws_size < xT_b + bin_b + seg_b + cnt_b) {
        cpad >>= 1;
        cnt_b = (size_t)N_OUT * cpad * sizeof(int);
    }
    const size_t need = xT_b + bin_b + seg_b + cnt_b;

    if (shape_ok && ws_size >= need) {
        char* p = (char*)d_ws;
        float* xT = (float*)p;        p += xT_b;
        uint2* binned = (uint2*)p;    p += bin_b;
        int* seg_total = (int*)p;     p += seg_b;
        int* cnt_pad = (int*)p;

        {
            dim3 blk(32, 32);
            xpose_in_kernel<<<(N_IN + 31) / 32, blk, 0, stream>>>(x, xT, N_IN);
        }
        hipMemsetAsync(cnt_pad, 0, cnt_b, stream);
        count_kernel<<<1024, 256, 0, stream>>>(dst, cnt_pad, NNZ, cpad);
        scanA_kernel<<<nseg, 1024, 0, stream>>>(cnt_pad, seg_total, N_OUT, cpad);
        scanB_kernel<<<1, 1024, 0, stream>>>(seg_total, nseg);
        scanC_kernel<<<nseg, 1024, 0, stream>>>(cnt_pad, seg_total, N_OUT, cpad);
        scatter_kernel<<<2048, 256, 0, stream>>>(src, dst, values, cnt_pad, binned, NNZ, cpad);
        gather_dst_kernel<<<(N_OUT + TJ - 1) / TJ, 256, 0, stream>>>(binned, cnt_pad, cpad,
                                                                     xT, bias, out, N_OUT);
    } else if (B == 32 && ws_size >= xT_b + (size_t)N_OUT * 32 * sizeof(float)) {
        // round-1 fallback: global atomics into accT
        float* xT = (float*)d_ws;
        float* accT = (float*)((char*)d_ws + xT_b);
        dim3 blk(32, 32);
        xpose_in_kernel<<<(N_IN + 31) / 32, blk, 0, stream>>>(x, xT, N_IN);
        hipMemsetAsync(accT, 0, (size_t)N_OUT * 32 * sizeof(float), stream);
        edge_kernel<<<4096, 256, 0, stream>>>(xT, values, src, dst, accT, NNZ);
        xpose_out_kernel<<<(N_OUT + 31) / 32, blk, 0, stream>>>(accT, bias, out, N_OUT);
    } else {
        long total = (long)N_OUT * B;
        init_out_bias_kernel<<<(int)((total + 255) / 256), 256, 0, stream>>>(out, bias, N_OUT, B);
        edge_direct_kernel<<<4096, 256, 0, stream>>>(x, values, src, dst, out, NNZ, N_IN, N_OUT);
    }
}

// Round 7
// 378.929 us; speedup vs baseline: 2.9413x; 1.5410x over previous
//
#include <hip/hip_runtime.h>

// SparseLinear: out[b, j] = sum_{e: dst[e]==j} values[e] * x[b, src[e]] + bias[j]
// Inputs: x f32 (B,N_IN,1) | values f32 (NNZ,) | bias f32 (N_OUT,1)
//         indices i32 (2,NNZ) row0=src row1=dst | n_out scalar
// Output: f32 (B, N_OUT, 1)
//
// Round-7 pipeline:
//   xpose -> count per 64-dst bucket (LDS hist) -> tiny scan ->
//   partition: LDS write-combined scatter into buckets (64B line flushes,
//              ~1.1M cursor atomics instead of 3.2M record atomics+stores) ->
//   gather_sort: per-bucket LDS chunk-sort by dst&63 fused with the proven
//              register-accumulate gather (no global per-dst offsets needed).

#define TJ 64
#define TJ_LOG 6
#define PACK_SHIFT 17          // src in bits [0,17), jl=dst&63 in [17,23)
#define SRC_MASK ((1u << PACK_SHIFT) - 1u)
#define NSB_MAX 1600
#define CAP 8                  // staged records per bucket (one 64B line)
#define A1_THREADS 512
#define A1_PER_THREAD 8
#define A1_BATCH (A1_THREADS * A1_PER_THREAD)   // 4096
#define CHUNK 2048             // gather_sort records per LDS chunk

// ---------- transpose x (B=32, N) -> xT (N, 32) ----------
__global__ void xpose_in_kernel(const float* __restrict__ x, float* __restrict__ xT, int N) {
    __shared__ float tile[32][33];
    int n0 = blockIdx.x * 32;
    int tx = threadIdx.x;
    int ty = threadIdx.y;
    if (n0 + tx < N) tile[ty][tx] = x[ty * (long)N + n0 + tx];
    __syncthreads();
    if (n0 + ty < N) xT[(long)(n0 + ty) * 32 + tx] = tile[tx][ty];
}

// ---------- count per bucket (LDS histogram; proven fast in r2-5) ----------
__global__ void count_sb_kernel(const int* __restrict__ dst, int* __restrict__ sb_cnt,
                                int nnz, int nsb) {
    __shared__ int hist[NSB_MAX];
    for (int i = threadIdx.x; i < nsb; i += blockDim.x) hist[i] = 0;
    __syncthreads();
    int tid = blockIdx.x * blockDim.x + threadIdx.x;
    int nth = gridDim.x * blockDim.x;
    int nvec = nnz >> 2;
    const int4* d4 = (const int4*)dst;
    for (int i = tid; i < nvec; i += nth) {
        int4 d = d4[i];
        atomicAdd(&hist[d.x >> TJ_LOG], 1);
        atomicAdd(&hist[d.y >> TJ_LOG], 1);
        atomicAdd(&hist[d.z >> TJ_LOG], 1);
        atomicAdd(&hist[d.w >> TJ_LOG], 1);
    }
    for (int e = (nvec << 2) + tid; e < nnz; e += nth)
        atomicAdd(&hist[dst[e] >> TJ_LOG], 1);
    __syncthreads();
    for (int i = threadIdx.x; i < nsb; i += blockDim.x) {
        int h = hist[i];
        if (h) atomicAdd(&sb_cnt[i], h);
    }
}

// ---------- exclusive scan of bucket counts -> sb_off; sb_cur = begin ----------
// single block, 256 threads, nsb <= 4096
__global__ void scan_sb_kernel(const int* __restrict__ sb_cnt, int* __restrict__ sb_off,
                               int* __restrict__ sb_cur, int nsb) {
    __shared__ int wave_sums[4];
    int tid = threadIdx.x;
    int items = (nsb + 255) >> 8;   // <= 16
    int base = tid * items;
    int local[16];
    int sum = 0;
    for (int k = 0; k < items; ++k) {
        int idx = base + k;
        int c = (idx < nsb) ? sb_cnt[idx] : 0;
        local[k] = sum;
        sum += c;
    }
    int lane = tid & 63, wid = tid >> 6;
    int inc = sum;
    for (int d = 1; d < 64; d <<= 1) {
        int n = __shfl_up(inc, d, 64);
        if (lane >= d) inc += n;
    }
    if (lane == 63) wave_sums[wid] = inc;
    __syncthreads();
    if (tid == 0) {
        int s = 0;
        for (int w = 0; w < 4; ++w) { int t = wave_sums[w]; wave_sums[w] = s; s += t; }
    }
    __syncthreads();
    int excl = inc - sum + wave_sums[wid];
    for (int k = 0; k < items; ++k) {
        int idx = base + k;
        if (idx < nsb) {
            int off = excl + local[k];
            sb_off[idx] = off;
            sb_cur[idx] = off;
        }
    }
    if (tid == 255) sb_off[nsb] = excl + sum;
}

// ---------- partition: LDS write-combined scatter into buckets ----------
__global__ __launch_bounds__(A1_THREADS) void partition_kernel(
        const int* __restrict__ src, const int* __restrict__ dst,
        const float* __restrict__ val, int* __restrict__ sb_cur,
        uint2* __restrict__ binA, int nnz, int nsb) {
    __shared__ uint2 stage[NSB_MAX * CAP];   // 102.4 KB
    __shared__ int scount[NSB_MAX];          // 6.4 KB
    for (int i = threadIdx.x; i < nsb; i += A1_THREADS) scount[i] = 0;
    __syncthreads();

    for (long base = (long)blockIdx.x * A1_BATCH; base < nnz;
         base += (long)gridDim.x * A1_BATCH) {
        uint2 rec[A1_PER_THREAD];
        int bkt[A1_PER_THREAD];
        bool placed[A1_PER_THREAD];
        int rem = 0;
#pragma unroll
        for (int q = 0; q < A1_PER_THREAD; ++q) placed[q] = true;

        int e0 = (int)base + threadIdx.x * A1_PER_THREAD;
        if (e0 < nnz) {
            if (e0 + A1_PER_THREAD <= nnz) {
                const int4* s4 = (const int4*)(src + e0);
                const int4* d4 = (const int4*)(dst + e0);
                const float4* v4 = (const float4*)(val + e0);
                int4 sa = s4[0], sb = s4[1];
                int4 da = d4[0], db = d4[1];
                float4 va = v4[0], vb = v4[1];
                int ss[8] = {sa.x, sa.y, sa.z, sa.w, sb.x, sb.y, sb.z, sb.w};
                int dd[8] = {da.x, da.y, da.z, da.w, db.x, db.y, db.z, db.w};
                float vv[8] = {va.x, va.y, va.z, va.w, vb.x, vb.y, vb.z, vb.w};
#pragma unroll
                for (int q = 0; q < 8; ++q) {
                    rec[q] = make_uint2((unsigned)ss[q] | ((unsigned)(dd[q] & (TJ - 1)) << PACK_SHIFT),
                                        __float_as_uint(vv[q]));
                    bkt[q] = dd[q] >> TJ_LOG;
                    placed[q] = false;
                    ++rem;
                }
            } else {
#pragma unroll
                for (int q = 0; q < 8; ++q) {
                    int e = e0 + q;
                    if (e < nnz) {
                        int d = dst[e];
                        rec[q] = make_uint2((unsigned)src[e] | ((unsigned)(d & (TJ - 1)) << PACK_SHIFT),
                                            __float_as_uint(val[e]));
                        bkt[q] = d >> TJ_LOG;
                        placed[q] = false;
                        ++rem;
                    }
                }
            }
        }

        while (true) {
#pragma unroll
            for (int q = 0; q < A1_PER_THREAD; ++q) {
                if (!placed[q]) {
                    int slot = atomicAdd(&scount[bkt[q]], 1);
                    if (slot < CAP) {
                        stage[bkt[q] * CAP + slot] = rec[q];
                        placed[q] = true;
                        --rem;
                    }
                }
            }
            __syncthreads();
            // flush: one thread per bucket writes a contiguous <=64B run
            for (int t = threadIdx.x; t < nsb; t += A1_THREADS) {
                int cc = scount[t];
                if (cc > CAP) cc = CAP;
                if (cc > 0) {
                    int g = atomicAdd(&sb_cur[t], cc);
                    for (int q = 0; q < cc; ++q) binA[g + q] = stage[t * CAP + q];
                }
                scount[t] = 0;
            }
            if (__syncthreads_count(rem) == 0) break;
        }
    }
}

// ---------- gather_sort: LDS chunk-sort by jl fused with register gather ----------
__global__ __launch_bounds__(256) void gather_sort_kernel(
        const uint2* __restrict__ binA, const int* __restrict__ sb_off,
        const float* __restrict__ xT, const float* __restrict__ bias,
        float* __restrict__ out, int n_out) {
    __shared__ uint2 raw[CHUNK];
    __shared__ uint2 srt[CHUNK];
    __shared__ int jcnt[TJ], joff[TJ], jcur[TJ];
    __shared__ float tile[TJ][33];
    int c = blockIdx.x;
    int j0 = c << TJ_LOG;
    int tid = threadIdx.x;
    int wv = tid >> 6, lane = tid & 63;
    int b = lane & 31, h = lane >> 5;
    int jlbase = wv * 16;

    float acc[16];
#pragma unroll
    for (int k = 0; k < 16; ++k) acc[k] = 0.0f;

    int pos = sb_off[c], end = sb_off[c + 1];
    while (pos < end) {
        int n = min(CHUNK, end - pos);
        for (int i = tid; i < n; i += 256) raw[i] = binA[pos + i];
        if (tid < TJ) jcnt[tid] = 0;
        __syncthreads();
        for (int i = tid; i < n; i += 256)
            atomicAdd(&jcnt[raw[i].x >> PACK_SHIFT], 1);
        __syncthreads();
        if (tid < 64) {
            int v = jcnt[tid];
            int inc = v;
            for (int d = 1; d < 64; d <<= 1) {
                int t = __shfl_up(inc, d, 64);
                if (lane >= d) inc += t;
            }
            joff[tid] = inc - v;
            jcur[tid] = inc - v;
        }
        __syncthreads();
        for (int i = tid; i < n; i += 256) {
            uint2 r = raw[i];
            int jl = (int)(r.x >> PACK_SHIFT);
            int p = atomicAdd(&jcur[jl], 1);
            srt[p] = r;
        }
        __syncthreads();

        int beg[16], cnt[16];
        int maxc = 0;
#pragma unroll
        for (int k = 0; k < 16; ++k) {
            beg[k] = joff[jlbase + k];
            cnt[k] = jcnt[jlbase + k];
            maxc = max(maxc, cnt[k]);
        }
        int maxT = (maxc + 1) >> 1;
        for (int tt = 0; tt < maxT; ++tt) {
            int t = (tt << 1) | h;
#pragma unroll
            for (int k = 0; k < 16; ++k) {
                if (t < cnt[k]) {
                    uint2 r = srt[beg[k] + t];
                    float xv = xT[((r.x & SRC_MASK) << 5) + b];
                    acc[k] += __uint_as_float(r.y) * xv;
                }
            }
        }
        __syncthreads();   // before reusing raw/srt/jcnt
        pos += n;
    }

#pragma unroll
    for (int k = 0; k < 16; ++k) {
        float a = acc[k] + __shfl_xor(acc[k], 32);
        if (h == 0) tile[jlbase + k][b] = a;
    }
    __syncthreads();
    for (int i = tid; i < TJ * 32; i += 256) {
        int bb = i >> TJ_LOG;
        int jl = i & (TJ - 1);
        int j = j0 + jl;
        if (j < n_out) out[bb * n_out + j] = tile[jl][bb] + bias[j];
    }
}

// ================= fallback (round-1 path, proven) =================
__global__ void edge_kernel(const float* __restrict__ xT, const float* __restrict__ values,
                            const int* __restrict__ src, const int* __restrict__ dst,
                            float* __restrict__ accT, int nnz) {
    int tid = blockIdx.x * blockDim.x + threadIdx.x;
    int lane_b = tid & 31;
    int e0 = tid >> 5;
    int estride = (gridDim.x * blockDim.x) >> 5;
    for (int e = e0; e < nnz; e += estride) {
        atomicAdd(&accT[(long)dst[e] * 32 + lane_b], values[e] * xT[(long)src[e] * 32 + lane_b]);
    }
}

__global__ void xpose_out_kernel(const float* __restrict__ accT, const float* __restrict__ bias,
                                 float* __restrict__ out, int N) {
    __shared__ float tile[32][33];
    int j0 = blockIdx.x * 32;
    int tx = threadIdx.x;
    int ty = threadIdx.y;
    if (j0 + ty < N) tile[ty][tx] = accT[(long)(j0 + ty) * 32 + tx];
    __syncthreads();
    if (j0 + tx < N) out[ty * (long)N + j0 + tx] = tile[tx][ty] + bias[j0 + tx];
}

__global__ void edge_direct_kernel(const float* __restrict__ x, const float* __restrict__ values,
                                   const int* __restrict__ src, const int* __restrict__ dst,
                                   float* __restrict__ out, int nnz, int N_IN, int N_OUT) {
    int tid = blockIdx.x * blockDim.x + threadIdx.x;
    int lane_b = tid & 31;
    int e0 = tid >> 5;
    int estride = (gridDim.x * blockDim.x) >> 5;
    for (int e = e0; e < nnz; e += estride) {
        atomicAdd(&out[(long)lane_b * N_OUT + dst[e]],
                  values[e] * x[(long)lane_b * N_IN + src[e]]);
    }
}

__global__ void init_out_bias_kernel(float* __restrict__ out, const float* __restrict__ bias,
                                     int N_OUT, int B) {
    long i = (long)blockIdx.x * blockDim.x + threadIdx.x;
    if (i < (long)N_OUT * B) out[i] = bias[i % N_OUT];
}

extern "C" void kernel_launch(void* const* d_in, const int* in_sizes, int n_in,
                              void* d_out, int out_size, void* d_ws, size_t ws_size,
                              hipStream_t stream) {
    const float* x      = (const float*)d_in[0];
    const float* values = (const float*)d_in[1];
    const float* bias   = (const float*)d_in[2];
    const int*   idx    = (const int*)d_in[3];

    const int NNZ   = in_sizes[1];
    const int N_OUT = in_sizes[2];
    const int B     = out_size / N_OUT;
    const int N_IN  = in_sizes[0] / B;

    const int* src = idx;
    const int* dst = idx + NNZ;
    float* out = (float*)d_out;

    const int nsb = (N_OUT + TJ - 1) >> TJ_LOG;

    const size_t xT_b   = (size_t)N_IN * 32 * sizeof(float);
    const size_t bin_b  = (size_t)NNZ * sizeof(uint2);
    const size_t sbc_b  = (size_t)nsb * sizeof(int);
    const size_t sbo_b  = (size_t)(nsb + 1) * sizeof(int);
    const size_t need   = xT_b + bin_b + sbc_b + sbo_b + sbc_b;

    const bool shape_ok = (B == 32) && (NNZ > 0) && (nsb <= NSB_MAX) &&
                          (N_IN <= (1 << PACK_SHIFT));

    if (shape_ok && ws_size >= need) {
        char* p = (char*)d_ws;
        float* xT = (float*)p;       p += xT_b;
        uint2* binA = (uint2*)p;     p += bin_b;
        int* sb_cnt = (int*)p;       p += sbc_b;
        int* sb_off = (int*)p;       p += sbo_b;
        int* sb_cur = (int*)p;

        {
            dim3 blk(32, 32);
            xpose_in_kernel<<<(N_IN + 31) / 32, blk, 0, stream>>>(x, xT, N_IN);
        }
        hipMemsetAsync(sb_cnt, 0, sbc_b, stream);
        count_sb_kernel<<<512, 256, 0, stream>>>(dst, sb_cnt, NNZ, nsb);
        scan_sb_kernel<<<1, 256, 0, stream>>>(sb_cnt, sb_off, sb_cur, nsb);
        partition_kernel<<<256, A1_THREADS, 0, stream>>>(src, dst, values, sb_cur, binA, NNZ, nsb);
        gather_sort_kernel<<<nsb, 256, 0, stream>>>(binA, sb_off, xT, bias, out, N_OUT);
    } else if (B == 32 && ws_size >= xT_b + (size_t)N_OUT * 32 * sizeof(float)) {
        // round-1 fallback: global atomics into accT (proven 349us)
        float* xT = (float*)d_ws;
        float* accT = (float*)((char*)d_ws + xT_b);
        dim3 blk(32, 32);
        xpose_in_kernel<<<(N_IN + 31) / 32, blk, 0, stream>>>(x, xT, N_IN);
        hipMemsetAsync(accT, 0, (size_t)N_OUT * 32 * sizeof(float), stream);
        edge_kernel<<<4096, 256, 0, stream>>>(xT, values, src, dst, accT, NNZ);
        xpose_out_kernel<<<(N_OUT + 31) / 32, blk, 0, stream>>>(accT, bias, out, N_OUT);
    } else {
        long total = (long)N_OUT * B;
        init_out_bias_kernel<<<(int)((total + 255) / 256), 256, 0, stream>>>(out, bias, N_OUT, B);
        edge_direct_kernel<<<4096, 256, 0, stream>>>(x, values, src, dst, out, NNZ, N_IN, N_OUT);
    }
}

// Round 8
// 298.252 us; speedup vs baseline: 3.7370x; 1.2705x over previous
//
#include <hip/hip_runtime.h>

// SparseLinear: out[b, j] = sum_{e: dst[e]==j} values[e] * x[b, src[e]] + bias[j]
// Inputs: x f32 (B,N_IN,1) | values f32 (NNZ,) | bias f32 (N_OUT,1)
//         indices i32 (2,NNZ) row0=src row1=dst | n_out scalar
// Output: f32 (B, N_OUT, 1)
//
// Round-8: same pipeline as round 7 (xpose -> bucket count -> scan ->
// write-combined partition -> fused sort+register-gather), but gather_sort
// LDS cut 42KB -> 17KB (single-buffer sort reading binA from global twice;
// epilogue tile aliased onto srt). Round-7 gather was latency-bound at 24%
// occupancy; this raises residency to ~8 blocks/CU.

#define TJ 64
#define TJ_LOG 6
#define PACK_SHIFT 17          // src in bits [0,17), jl=dst&63 in [17,23)
#define SRC_MASK ((1u << PACK_SHIFT) - 1u)
#define NSB_MAX 1600
#define CAP 8                  // staged records per bucket (one 64B line)
#define A1_THREADS 512
#define A1_PER_THREAD 8
#define A1_BATCH (A1_THREADS * A1_PER_THREAD)   // 4096
#define CHUNK 2048             // gather_sort records per LDS chunk

// ---------- transpose x (B=32, N) -> xT (N, 32) ----------
__global__ void xpose_in_kernel(const float* __restrict__ x, float* __restrict__ xT, int N) {
    __shared__ float tile[32][33];
    int n0 = blockIdx.x * 32;
    int tx = threadIdx.x;
    int ty = threadIdx.y;
    if (n0 + tx < N) tile[ty][tx] = x[ty * (long)N + n0 + tx];
    __syncthreads();
    if (n0 + ty < N) xT[(long)(n0 + ty) * 32 + tx] = tile[tx][ty];
}

// ---------- count per bucket (LDS histogram) ----------
__global__ void count_sb_kernel(const int* __restrict__ dst, int* __restrict__ sb_cnt,
                                int nnz, int nsb) {
    __shared__ int hist[NSB_MAX];
    for (int i = threadIdx.x; i < nsb; i += blockDim.x) hist[i] = 0;
    __syncthreads();
    int tid = blockIdx.x * blockDim.x + threadIdx.x;
    int nth = gridDim.x * blockDim.x;
    int nvec = nnz >> 2;
    const int4* d4 = (const int4*)dst;
    for (int i = tid; i < nvec; i += nth) {
        int4 d = d4[i];
        atomicAdd(&hist[d.x >> TJ_LOG], 1);
        atomicAdd(&hist[d.y >> TJ_LOG], 1);
        atomicAdd(&hist[d.z >> TJ_LOG], 1);
        atomicAdd(&hist[d.w >> TJ_LOG], 1);
    }
    for (int e = (nvec << 2) + tid; e < nnz; e += nth)
        atomicAdd(&hist[dst[e] >> TJ_LOG], 1);
    __syncthreads();
    for (int i = threadIdx.x; i < nsb; i += blockDim.x) {
        int h = hist[i];
        if (h) atomicAdd(&sb_cnt[i], h);
    }
}

// ---------- exclusive scan of bucket counts -> sb_off; sb_cur = begin ----------
__global__ void scan_sb_kernel(const int* __restrict__ sb_cnt, int* __restrict__ sb_off,
                               int* __restrict__ sb_cur, int nsb) {
    __shared__ int wave_sums[4];
    int tid = threadIdx.x;
    int items = (nsb + 255) >> 8;   // <= 16
    int base = tid * items;
    int local[16];
    int sum = 0;
    for (int k = 0; k < items; ++k) {
        int idx = base + k;
        int c = (idx < nsb) ? sb_cnt[idx] : 0;
        local[k] = sum;
        sum += c;
    }
    int lane = tid & 63, wid = tid >> 6;
    int inc = sum;
    for (int d = 1; d < 64; d <<= 1) {
        int n = __shfl_up(inc, d, 64);
        if (lane >= d) inc += n;
    }
    if (lane == 63) wave_sums[wid] = inc;
    __syncthreads();
    if (tid == 0) {
        int s = 0;
        for (int w = 0; w < 4; ++w) { int t = wave_sums[w]; wave_sums[w] = s; s += t; }
    }
    __syncthreads();
    int excl = inc - sum + wave_sums[wid];
    for (int k = 0; k < items; ++k) {
        int idx = base + k;
        if (idx < nsb) {
            int off = excl + local[k];
            sb_off[idx] = off;
            sb_cur[idx] = off;
        }
    }
    if (tid == 255) sb_off[nsb] = excl + sum;
}

// ---------- partition: LDS write-combined scatter into buckets ----------
__global__ __launch_bounds__(A1_THREADS) void partition_kernel(
        const int* __restrict__ src, const int* __restrict__ dst,
        const float* __restrict__ val, int* __restrict__ sb_cur,
        uint2* __restrict__ binA, int nnz, int nsb) {
    __shared__ uint2 stage[NSB_MAX * CAP];   // 102.4 KB
    __shared__ int scount[NSB_MAX];          // 6.4 KB
    for (int i = threadIdx.x; i < nsb; i += A1_THREADS) scount[i] = 0;
    __syncthreads();

    for (long base = (long)blockIdx.x * A1_BATCH; base < nnz;
         base += (long)gridDim.x * A1_BATCH) {
        uint2 rec[A1_PER_THREAD];
        int bkt[A1_PER_THREAD];
        bool placed[A1_PER_THREAD];
        int rem = 0;
#pragma unroll
        for (int q = 0; q < A1_PER_THREAD; ++q) placed[q] = true;

        int e0 = (int)base + threadIdx.x * A1_PER_THREAD;
        if (e0 < nnz) {
            if (e0 + A1_PER_THREAD <= nnz) {
                const int4* s4 = (const int4*)(src + e0);
                const int4* d4 = (const int4*)(dst + e0);
                const float4* v4 = (const float4*)(val + e0);
                int4 sa = s4[0], sb = s4[1];
                int4 da = d4[0], db = d4[1];
                float4 va = v4[0], vb = v4[1];
                int ss[8] = {sa.x, sa.y, sa.z, sa.w, sb.x, sb.y, sb.z, sb.w};
                int dd[8] = {da.x, da.y, da.z, da.w, db.x, db.y, db.z, db.w};
                float vv[8] = {va.x, va.y, va.z, va.w, vb.x, vb.y, vb.z, vb.w};
#pragma unroll
                for (int q = 0; q < 8; ++q) {
                    rec[q] = make_uint2((unsigned)ss[q] | ((unsigned)(dd[q] & (TJ - 1)) << PACK_SHIFT),
                                        __float_as_uint(vv[q]));
                    bkt[q] = dd[q] >> TJ_LOG;
                    placed[q] = false;
                    ++rem;
                }
            } else {
#pragma unroll
                for (int q = 0; q < 8; ++q) {
                    int e = e0 + q;
                    if (e < nnz) {
                        int d = dst[e];
                        rec[q] = make_uint2((unsigned)src[e] | ((unsigned)(d & (TJ - 1)) << PACK_SHIFT),
                                            __float_as_uint(val[e]));
                        bkt[q] = d >> TJ_LOG;
                        placed[q] = false;
                        ++rem;
                    }
                }
            }
        }

        while (true) {
#pragma unroll
            for (int q = 0; q < A1_PER_THREAD; ++q) {
                if (!placed[q]) {
                    int slot = atomicAdd(&scount[bkt[q]], 1);
                    if (slot < CAP) {
                        stage[bkt[q] * CAP + slot] = rec[q];
                        placed[q] = true;
                        --rem;
                    }
                }
            }
            __syncthreads();
            for (int t = threadIdx.x; t < nsb; t += A1_THREADS) {
                int cc = scount[t];
                if (cc > CAP) cc = CAP;
                if (cc > 0) {
                    int g = atomicAdd(&sb_cur[t], cc);
                    for (int q = 0; q < cc; ++q) binA[g + q] = stage[t * CAP + q];
                }
                scount[t] = 0;
            }
            if (__syncthreads_count(rem) == 0) break;
        }
    }
}

// ---------- gather_sort: single-buffer LDS sort fused with register gather ----------
__global__ __launch_bounds__(256) void gather_sort_kernel(
        const uint2* __restrict__ binA, const int* __restrict__ sb_off,
        const float* __restrict__ xT, const float* __restrict__ bias,
        float* __restrict__ out, int n_out) {
    __shared__ __align__(16) char smem[CHUNK * sizeof(uint2)];  // 16 KB: srt, then tile
    __shared__ int jcnt[TJ], joff[TJ], jcur[TJ];
    uint2* srt = (uint2*)smem;
    float (*tile)[33] = (float (*)[33])smem;                    // alias, used after loop

    int c = blockIdx.x;
    int j0 = c << TJ_LOG;
    int tid = threadIdx.x;
    int wv = tid >> 6, lane = tid & 63;
    int b = lane & 31, h = lane >> 5;
    int jlbase = wv * 16;

    float acc[16];
#pragma unroll
    for (int k = 0; k < 16; ++k) acc[k] = 0.0f;

    int pos = sb_off[c], end = sb_off[c + 1];
    while (pos < end) {
        int n = min(CHUNK, end - pos);
        // 1) histogram of jl (records streamed from global, coalesced)
        if (tid < TJ) jcnt[tid] = 0;
        __syncthreads();
        for (int i = tid; i < n; i += 256)
            atomicAdd(&jcnt[binA[pos + i].x >> PACK_SHIFT], 1);
        __syncthreads();
        // 2) exclusive scan over 64 bins (wave 0)
        if (tid < 64) {
            int v = jcnt[tid];
            int inc = v;
            for (int d = 1; d < 64; d <<= 1) {
                int t = __shfl_up(inc, d, 64);
                if (lane >= d) inc += t;
            }
            joff[tid] = inc - v;
            jcur[tid] = inc - v;
        }
        __syncthreads();
        // 3) scatter into srt (re-read binA, L2-hot)
        for (int i = tid; i < n; i += 256) {
            uint2 r = binA[pos + i];
            int jl = (int)(r.x >> PACK_SHIFT);
            int p = atomicAdd(&jcur[jl], 1);
            srt[p] = r;
        }
        __syncthreads();
        // 4) register-accumulate from sorted records
        int beg[16], cnt[16];
        int maxc = 0;
#pragma unroll
        for (int k = 0; k < 16; ++k) {
            beg[k] = joff[jlbase + k];
            cnt[k] = jcnt[jlbase + k];
            maxc = max(maxc, cnt[k]);
        }
        int maxT = (maxc + 1) >> 1;
        for (int tt = 0; tt < maxT; ++tt) {
            int t = (tt << 1) | h;
#pragma unroll
            for (int k = 0; k < 16; ++k) {
                if (t < cnt[k]) {
                    uint2 r = srt[beg[k] + t];
                    float xv = xT[((r.x & SRC_MASK) << 5) + b];
                    acc[k] += __uint_as_float(r.y) * xv;
                }
            }
        }
        __syncthreads();   // srt dead after this point in the iteration
        pos += n;
    }

    // epilogue: tile aliases srt (all srt reads completed before last barrier)
#pragma unroll
    for (int k = 0; k < 16; ++k) {
        float a = acc[k] + __shfl_xor(acc[k], 32);
        if (h == 0) tile[jlbase + k][b] = a;
    }
    __syncthreads();
    for (int i = tid; i < TJ * 32; i += 256) {
        int bb = i >> TJ_LOG;
        int jl = i & (TJ - 1);
        int j = j0 + jl;
        if (j < n_out) out[bb * n_out + j] = tile[jl][bb] + bias[j];
    }
}

// ================= fallback (round-1 path, proven) =================
__global__ void edge_kernel(const float* __restrict__ xT, const float* __restrict__ values,
                            const int* __restrict__ src, const int* __restrict__ dst,
                            float* __restrict__ accT, int nnz) {
    int tid = blockIdx.x * blockDim.x + threadIdx.x;
    int lane_b = tid & 31;
    int e0 = tid >> 5;
    int estride = (gridDim.x * blockDim.x) >> 5;
    for (int e = e0; e < nnz; e += estride) {
        atomicAdd(&accT[(long)dst[e] * 32 + lane_b], values[e] * xT[(long)src[e] * 32 + lane_b]);
    }
}

__global__ void xpose_out_kernel(const float* __restrict__ accT, const float* __restrict__ bias,
                                 float* __restrict__ out, int N) {
    __shared__ float tile[32][33];
    int j0 = blockIdx.x * 32;
    int tx = threadIdx.x;
    int ty = threadIdx.y;
    if (j0 + ty < N) tile[ty][tx] = accT[(long)(j0 + ty) * 32 + tx];
    __syncthreads();
    if (j0 + tx < N) out[ty * (long)N + j0 + tx] = tile[tx][ty] + bias[j0 + tx];
}

__global__ void edge_direct_kernel(const float* __restrict__ x, const float* __restrict__ values,
                                   const int* __restrict__ src, const int* __restrict__ dst,
                                   float* __restrict__ out, int nnz, int N_IN, int N_OUT) {
    int tid = blockIdx.x * blockDim.x + threadIdx.x;
    int lane_b = tid & 31;
    int e0 = tid >> 5;
    int estride = (gridDim.x * blockDim.x) >> 5;
    for (int e = e0; e < nnz; e += estride) {
        atomicAdd(&out[(long)lane_b * N_OUT + dst[e]],
                  values[e] * x[(long)lane_b * N_IN + src[e]]);
    }
}

__global__ void init_out_bias_kernel(float* __restrict__ out, const float* __restrict__ bias,
                                     int N_OUT, int B) {
    long i = (long)blockIdx.x * blockDim.x + threadIdx.x;
    if (i < (long)N_OUT * B) out[i] = bias[i % N_OUT];
}

extern "C" void kernel_launch(void* const* d_in, const int* in_sizes, int n_in,
                              void* d_out, int out_size, void* d_ws, size_t ws_size,
                              hipStream_t stream) {
    const float* x      = (const float*)d_in[0];
    const float* values = (const float*)d_in[1];
    const float* bias   = (const float*)d_in[2];
    const int*   idx    = (const int*)d_in[3];

    const int NNZ   = in_sizes[1];
    const int N_OUT = in_sizes[2];
    const int B     = out_size / N_OUT;
    const int N_IN  = in_sizes[0] / B;

    const int* src = idx;
    const int* dst = idx + NNZ;
    float* out = (float*)d_out;

    const int nsb = (N_OUT + TJ - 1) >> TJ_LOG;

    const size_t xT_b   = (size_t)N_IN * 32 * sizeof(float);
    const size_t bin_b  = (size_t)NNZ * sizeof(uint2);
    const size_t sbc_b  = (size_t)nsb * sizeof(int);
    const size_t sbo_b  = (size_t)(nsb + 1) * sizeof(int);
    const size_t need   = xT_b + bin_b + sbc_b + sbo_b + sbc_b;

    const bool shape_ok = (B == 32) && (NNZ > 0) && (nsb <= NSB_MAX) &&
                          (N_IN <= (1 << PACK_SHIFT));

    if (shape_ok && ws_size >= need) {
        char* p = (char*)d_ws;
        float* xT = (float*)p;       p += xT_b;
        uint2* binA = (uint2*)p;     p += bin_b;
        int* sb_cnt = (int*)p;       p += sbc_b;
        int* sb_off = (int*)p;       p += sbo_b;
        int* sb_cur = (int*)p;

        {
            dim3 blk(32, 32);
            xpose_in_kernel<<<(N_IN + 31) / 32, blk, 0, stream>>>(x, xT, N_IN);
        }
        hipMemsetAsync(sb_cnt, 0, sbc_b, stream);
        count_sb_kernel<<<512, 256, 0, stream>>>(dst, sb_cnt, NNZ, nsb);
        scan_sb_kernel<<<1, 256, 0, stream>>>(sb_cnt, sb_off, sb_cur, nsb);
        partition_kernel<<<256, A1_THREADS, 0, stream>>>(src, dst, values, sb_cur, binA, NNZ, nsb);
        gather_sort_kernel<<<nsb, 256, 0, stream>>>(binA, sb_off, xT, bias, out, N_OUT);
    } else if (B == 32 && ws_size >= xT_b + (size_t)N_OUT * 32 * sizeof(float)) {
        float* xT = (float*)d_ws;
        float* accT = (float*)((char*)d_ws + xT_b);
        dim3 blk(32, 32);
        xpose_in_kernel<<<(N_IN + 31) / 32, blk, 0, stream>>>(x, xT, N_IN);
        hipMemsetAsync(accT, 0, (size_t)N_OUT * 32 * sizeof(float), stream);
        edge_kernel<<<4096, 256, 0, stream>>>(xT, values, src, dst, accT, NNZ);
        xpose_out_kernel<<<(N_OUT + 31) / 32, blk, 0, stream>>>(accT, bias, out, N_OUT);
    } else {
        long total = (long)N_OUT * B;
        init_out_bias_kernel<<<(int)((total + 255) / 256), 256, 0, stream>>>(out, bias, N_OUT, B);
        edge_direct_kernel<<<4096, 256, 0, stream>>>(x, values, src, dst, out, NNZ, N_IN, N_OUT);
    }
}

// Round 9
// 208.556 us; speedup vs baseline: 5.3442x; 1.4301x over previous
//
#include <hip/hip_runtime.h>

// SparseLinear: out[b, j] = sum_{e: dst[e]==j} values[e] * x[b, src[e]] + bias[j]
// Inputs: x f32 (B,N_IN,1) | values f32 (NNZ,) | bias f32 (N_OUT,1)
//         indices i32 (2,NNZ) row0=src row1=dst | n_out scalar
// Output: f32 (B, N_OUT, 1)
//
// Round-9: gather_sort rebuilt: 512-thread blocks (thread-cap 4 blocks/CU =
// 100% static occupancy), per-k LINEAR walk of the sorted runs (1 FMA chain
// per k, independent pipelinable loads) replacing the 16-k lockstep with
// divergent conditionals (r8: 34% occ, VALU 11%, latency-bound).

#define TJ 64
#define TJ_LOG 6
#define PACK_SHIFT 17          // src in bits [0,17), jl=dst&63 in [17,23)
#define SRC_MASK ((1u << PACK_SHIFT) - 1u)
#define NSB_MAX 1600
#define CAP 8                  // staged records per bucket (one 64B line)
#define A1_THREADS 512
#define A1_PER_THREAD 8
#define A1_BATCH (A1_THREADS * A1_PER_THREAD)   // 4096
#define CHUNK 2048             // gather_sort records per LDS chunk
#define GT 512                 // gather threads (8 waves)

// ---------- transpose x (B=32, N) -> xT (N, 32) ----------
__global__ void xpose_in_kernel(const float* __restrict__ x, float* __restrict__ xT, int N) {
    __shared__ float tile[32][33];
    int n0 = blockIdx.x * 32;
    int tx = threadIdx.x;
    int ty = threadIdx.y;
    if (n0 + tx < N) tile[ty][tx] = x[ty * (long)N + n0 + tx];
    __syncthreads();
    if (n0 + ty < N) xT[(long)(n0 + ty) * 32 + tx] = tile[tx][ty];
}

// ---------- count per bucket (LDS histogram) ----------
__global__ void count_sb_kernel(const int* __restrict__ dst, int* __restrict__ sb_cnt,
                                int nnz, int nsb) {
    __shared__ int hist[NSB_MAX];
    for (int i = threadIdx.x; i < nsb; i += blockDim.x) hist[i] = 0;
    __syncthreads();
    int tid = blockIdx.x * blockDim.x + threadIdx.x;
    int nth = gridDim.x * blockDim.x;
    int nvec = nnz >> 2;
    const int4* d4 = (const int4*)dst;
    for (int i = tid; i < nvec; i += nth) {
        int4 d = d4[i];
        atomicAdd(&hist[d.x >> TJ_LOG], 1);
        atomicAdd(&hist[d.y >> TJ_LOG], 1);
        atomicAdd(&hist[d.z >> TJ_LOG], 1);
        atomicAdd(&hist[d.w >> TJ_LOG], 1);
    }
    for (int e = (nvec << 2) + tid; e < nnz; e += nth)
        atomicAdd(&hist[dst[e] >> TJ_LOG], 1);
    __syncthreads();
    for (int i = threadIdx.x; i < nsb; i += blockDim.x) {
        int h = hist[i];
        if (h) atomicAdd(&sb_cnt[i], h);
    }
}

// ---------- exclusive scan of bucket counts -> sb_off; sb_cur = begin ----------
__global__ void scan_sb_kernel(const int* __restrict__ sb_cnt, int* __restrict__ sb_off,
                               int* __restrict__ sb_cur, int nsb) {
    __shared__ int wave_sums[4];
    int tid = threadIdx.x;
    int items = (nsb + 255) >> 8;   // <= 16
    int base = tid * items;
    int local[16];
    int sum = 0;
    for (int k = 0; k < items; ++k) {
        int idx = base + k;
        int c = (idx < nsb) ? sb_cnt[idx] : 0;
        local[k] = sum;
        sum += c;
    }
    int lane = tid & 63, wid = tid >> 6;
    int inc = sum;
    for (int d = 1; d < 64; d <<= 1) {
        int n = __shfl_up(inc, d, 64);
        if (lane >= d) inc += n;
    }
    if (lane == 63) wave_sums[wid] = inc;
    __syncthreads();
    if (tid == 0) {
        int s = 0;
        for (int w = 0; w < 4; ++w) { int t = wave_sums[w]; wave_sums[w] = s; s += t; }
    }
    __syncthreads();
    int excl = inc - sum + wave_sums[wid];
    for (int k = 0; k < items; ++k) {
        int idx = base + k;
        if (idx < nsb) {
            int off = excl + local[k];
            sb_off[idx] = off;
            sb_cur[idx] = off;
        }
    }
    if (tid == 255) sb_off[nsb] = excl + sum;
}

// ---------- partition: LDS write-combined scatter into buckets ----------
__global__ __launch_bounds__(A1_THREADS) void partition_kernel(
        const int* __restrict__ src, const int* __restrict__ dst,
        const float* __restrict__ val, int* __restrict__ sb_cur,
        uint2* __restrict__ binA, int nnz, int nsb) {
    __shared__ uint2 stage[NSB_MAX * CAP];   // 102.4 KB
    __shared__ int scount[NSB_MAX];          // 6.4 KB
    for (int i = threadIdx.x; i < nsb; i += A1_THREADS) scount[i] = 0;
    __syncthreads();

    for (long base = (long)blockIdx.x * A1_BATCH; base < nnz;
         base += (long)gridDim.x * A1_BATCH) {
        uint2 rec[A1_PER_THREAD];
        int bkt[A1_PER_THREAD];
        bool placed[A1_PER_THREAD];
        int rem = 0;
#pragma unroll
        for (int q = 0; q < A1_PER_THREAD; ++q) placed[q] = true;

        int e0 = (int)base + threadIdx.x * A1_PER_THREAD;
        if (e0 < nnz) {
            if (e0 + A1_PER_THREAD <= nnz) {
                const int4* s4 = (const int4*)(src + e0);
                const int4* d4 = (const int4*)(dst + e0);
                const float4* v4 = (const float4*)(val + e0);
                int4 sa = s4[0], sb = s4[1];
                int4 da = d4[0], db = d4[1];
                float4 va = v4[0], vb = v4[1];
                int ss[8] = {sa.x, sa.y, sa.z, sa.w, sb.x, sb.y, sb.z, sb.w};
                int dd[8] = {da.x, da.y, da.z, da.w, db.x, db.y, db.z, db.w};
                float vv[8] = {va.x, va.y, va.z, va.w, vb.x, vb.y, vb.z, vb.w};
#pragma unroll
                for (int q = 0; q < 8; ++q) {
                    rec[q] = make_uint2((unsigned)ss[q] | ((unsigned)(dd[q] & (TJ - 1)) << PACK_SHIFT),
                                        __float_as_uint(vv[q]));
                    bkt[q] = dd[q] >> TJ_LOG;
                    placed[q] = false;
                    ++rem;
                }
            } else {
#pragma unroll
                for (int q = 0; q < 8; ++q) {
                    int e = e0 + q;
                    if (e < nnz) {
                        int d = dst[e];
                        rec[q] = make_uint2((unsigned)src[e] | ((unsigned)(d & (TJ - 1)) << PACK_SHIFT),
                                            __float_as_uint(val[e]));
                        bkt[q] = d >> TJ_LOG;
                        placed[q] = false;
                        ++rem;
                    }
                }
            }
        }

        while (true) {
#pragma unroll
            for (int q = 0; q < A1_PER_THREAD; ++q) {
                if (!placed[q]) {
                    int slot = atomicAdd(&scount[bkt[q]], 1);
                    if (slot < CAP) {
                        stage[bkt[q] * CAP + slot] = rec[q];
                        placed[q] = true;
                        --rem;
                    }
                }
            }
            __syncthreads();
            for (int t = threadIdx.x; t < nsb; t += A1_THREADS) {
                int cc = scount[t];
                if (cc > CAP) cc = CAP;
                if (cc > 0) {
                    int g = atomicAdd(&sb_cur[t], cc);
                    for (int q = 0; q < cc; ++q) binA[g + q] = stage[t * CAP + q];
                }
                scount[t] = 0;
            }
            if (__syncthreads_count(rem) == 0) break;
        }
    }
}

// ---------- gather_sort: 512 threads, per-k linear walk of sorted runs ----------
__global__ __launch_bounds__(GT) void gather_sort_kernel(
        const uint2* __restrict__ binA, const int* __restrict__ sb_off,
        const float* __restrict__ xT, const float* __restrict__ bias,
        float* __restrict__ out, int n_out) {
    __shared__ __align__(16) char smem[CHUNK * sizeof(uint2)];  // 16 KB: srt, then tile
    __shared__ int joff[TJ], jcur[TJ];
    uint2* srt = (uint2*)smem;
    float (*tile)[33] = (float (*)[33])smem;                    // alias, used after loop

    int c = blockIdx.x;
    int j0 = c << TJ_LOG;
    int tid = threadIdx.x;
    int wv = tid >> 6, lane = tid & 63;
    int b = lane & 31, h = lane >> 5;
    int k0 = wv * 8;                 // 8 waves x 8 j's

    float acc[8];
#pragma unroll
    for (int k = 0; k < 8; ++k) acc[k] = 0.0f;

    int pos = sb_off[c], end = sb_off[c + 1];
    while (pos < end) {
        int n = min(CHUNK, end - pos);
        // 1) histogram of jl (records streamed from global, coalesced)
        if (tid < TJ) jcur[tid] = 0;
        __syncthreads();
        for (int i = tid; i < n; i += GT)
            atomicAdd(&jcur[binA[pos + i].x >> PACK_SHIFT], 1);
        __syncthreads();
        // 2) exclusive scan over 64 bins (wave 0); jcur becomes running cursor
        if (tid < 64) {
            int v = jcur[tid];
            int inc = v;
            for (int d = 1; d < 64; d <<= 1) {
                int t = __shfl_up(inc, d, 64);
                if (lane >= d) inc += t;
            }
            joff[tid] = inc - v;
            jcur[tid] = inc - v;
        }
        __syncthreads();
        // 3) scatter into srt (re-read binA, L2-hot); after this jcur[k] = run end
        for (int i = tid; i < n; i += GT) {
            uint2 r = binA[pos + i];
            int jl = (int)(r.x >> PACK_SHIFT);
            int p = atomicAdd(&jcur[jl], 1);
            srt[p] = r;
        }
        __syncthreads();
        // 4) per-k linear walk: contiguous sorted run, halves split by parity
#pragma unroll
        for (int k = 0; k < 8; ++k) {
            int kk = k0 + k;
            int s1 = jcur[kk];                 // run end
            float a = 0.0f;
            for (int t = joff[kk] + h; t < s1; t += 2) {
                uint2 r = srt[t];              // half-wave broadcast (free)
                float xv = xT[((r.x & SRC_MASK) << 5) + b];
                a += __uint_as_float(r.y) * xv;
            }
            acc[k] += a;
        }
        __syncthreads();   // srt dead after this point in the iteration
        pos += n;
    }

    // epilogue: tile aliases srt
#pragma unroll
    for (int k = 0; k < 8; ++k) {
        float a = acc[k] + __shfl_xor(acc[k], 32);
        if (h == 0) tile[k0 + k][b] = a;
    }
    __syncthreads();
    for (int i = tid; i < TJ * 32; i += GT) {
        int bb = i >> TJ_LOG;
        int jl = i & (TJ - 1);
        int j = j0 + jl;
        if (j < n_out) out[bb * n_out + j] = tile[jl][bb] + bias[j];
    }
}

// ================= fallback (round-1 path, proven) =================
__global__ void edge_kernel(const float* __restrict__ xT, const float* __restrict__ values,
                            const int* __restrict__ src, const int* __restrict__ dst,
                            float* __restrict__ accT, int nnz) {
    int tid = blockIdx.x * blockDim.x + threadIdx.x;
    int lane_b = tid & 31;
    int e0 = tid >> 5;
    int estride = (gridDim.x * blockDim.x) >> 5;
    for (int e = e0; e < nnz; e += estride) {
        atomicAdd(&accT[(long)dst[e] * 32 + lane_b], values[e] * xT[(long)src[e] * 32 + lane_b]);
    }
}

__global__ void xpose_out_kernel(const float* __restrict__ accT, const float* __restrict__ bias,
                                 float* __restrict__ out, int N) {
    __shared__ float tile[32][33];
    int j0 = blockIdx.x * 32;
    int tx = threadIdx.x;
    int ty = threadIdx.y;
    if (j0 + ty < N) tile[ty][tx] = accT[(long)(j0 + ty) * 32 + tx];
    __syncthreads();
    if (j0 + tx < N) out[ty * (long)N + j0 + tx] = tile[tx][ty] + bias[j0 + tx];
}

__global__ void edge_direct_kernel(const float* __restrict__ x, const float* __restrict__ values,
                                   const int* __restrict__ src, const int* __restrict__ dst,
                                   float* __restrict__ out, int nnz, int N_IN, int N_OUT) {
    int tid = blockIdx.x * blockDim.x + threadIdx.x;
    int lane_b = tid & 31;
    int e0 = tid >> 5;
    int estride = (gridDim.x * blockDim.x) >> 5;
    for (int e = e0; e < nnz; e += estride) {
        atomicAdd(&out[(long)lane_b * N_OUT + dst[e]],
                  values[e] * x[(long)lane_b * N_IN + src[e]]);
    }
}

__global__ void init_out_bias_kernel(float* __restrict__ out, const float* __restrict__ bias,
                                     int N_OUT, int B) {
    long i = (long)blockIdx.x * blockDim.x + threadIdx.x;
    if (i < (long)N_OUT * B) out[i] = bias[i % N_OUT];
}

extern "C" void kernel_launch(void* const* d_in, const int* in_sizes, int n_in,
                              void* d_out, int out_size, void* d_ws, size_t ws_size,
                              hipStream_t stream) {
    const float* x      = (const float*)d_in[0];
    const float* values = (const float*)d_in[1];
    const float* bias   = (const float*)d_in[2];
    const int*   idx    = (const int*)d_in[3];

    const int NNZ   = in_sizes[1];
    const int N_OUT = in_sizes[2];
    const int B     = out_size / N_OUT;
    const int N_IN  = in_sizes[0] / B;

    const int* src = idx;
    const int* dst = idx + NNZ;
    float* out = (float*)d_out;

    const int nsb = (N_OUT + TJ - 1) >> TJ_LOG;

    const size_t xT_b   = (size_t)N_IN * 32 * sizeof(float);
    const size_t bin_b  = (size_t)NNZ * sizeof(uint2);
    const size_t sbc_b  = (size_t)nsb * sizeof(int);
    const size_t sbo_b  = (size_t)(nsb + 1) * sizeof(int);
    const size_t need   = xT_b + bin_b + sbc_b + sbo_b + sbc_b;

    const bool shape_ok = (B == 32) && (NNZ > 0) && (nsb <= NSB_MAX) &&
                          (N_IN <= (1 << PACK_SHIFT));

    if (shape_ok && ws_size >= need) {
        char* p = (char*)d_ws;
        float* xT = (float*)p;       p += xT_b;
        uint2* binA = (uint2*)p;     p += bin_b;
        int* sb_cnt = (int*)p;       p += sbc_b;
        int* sb_off = (int*)p;       p += sbo_b;
        int* sb_cur = (int*)p;

        {
            dim3 blk(32, 32);
            xpose_in_kernel<<<(N_IN + 31) / 32, blk, 0, stream>>>(x, xT, N_IN);
        }
        hipMemsetAsync(sb_cnt, 0, sbc_b, stream);
        count_sb_kernel<<<512, 256, 0, stream>>>(dst, sb_cnt, NNZ, nsb);
        scan_sb_kernel<<<1, 256, 0, stream>>>(sb_cnt, sb_off, sb_cur, nsb);
        partition_kernel<<<256, A1_THREADS, 0, stream>>>(src, dst, values, sb_cur, binA, NNZ, nsb);
        gather_sort_kernel<<<nsb, GT, 0, stream>>>(binA, sb_off, xT, bias, out, N_OUT);
    } else if (B == 32 && ws_size >= xT_b + (size_t)N_OUT * 32 * sizeof(float)) {
        float* xT = (float*)d_ws;
        float* accT = (float*)((char*)d_ws + xT_b);
        dim3 blk(32, 32);
        xpose_in_kernel<<<(N_IN + 31) / 32, blk, 0, stream>>>(x, xT, N_IN);
        hipMemsetAsync(accT, 0, (size_t)N_OUT * 32 * sizeof(float), stream);
        edge_kernel<<<4096, 256, 0, stream>>>(xT, values, src, dst, accT, NNZ);
        xpose_out_kernel<<<(N_OUT + 31) / 32, blk, 0, stream>>>(accT, bias, out, N_OUT);
    } else {
        long total = (long)N_OUT * B;
        init_out_bias_kernel<<<(int)((total + 255) / 256), 256, 0, stream>>>(out, bias, N_OUT, B);
        edge_direct_kernel<<<4096, 256, 0, stream>>>(x, values, src, dst, out, NNZ, N_IN, N_OUT);
    }
}